// Round 7
// baseline (1101.952 us; speedup 1.0000x reference)
//
#include <hip/hip_runtime.h>

#define NN 4681        // total nodes
#define NI 585         // internal (parent) nodes
#define GRID 703

__device__ __forceinline__ float sigm(float x) { return 1.f / (1.f + expf(-x)); }

struct Smem {
  union {
    struct { float As[16][132]; float Bs[16][68]; int toks[128]; } g;
    struct { float hs[300]; float siou[900]; float sc[300]; float sh[300]; } n;
  };
};

// Device-scope grid barrier: all GRID blocks co-resident by construction.
// Arrival: one atomic add. Poll: relaxed agent-scope LOAD (no RMW contention).
__device__ __forceinline__ void gsync(unsigned* bar, int k) {
  __syncthreads();
  if (threadIdx.x == 0) {
    __threadfence();                       // release: flush this block's writes
    __hip_atomic_fetch_add(&bar[k], 1u, __ATOMIC_RELAXED, __HIP_MEMORY_SCOPE_AGENT);
    long tries = 0;
    while (__hip_atomic_load(&bar[k], __ATOMIC_RELAXED, __HIP_MEMORY_SCOPE_AGENT)
           < (unsigned)GRID) {
      __builtin_amdgcn_s_sleep(2);
      if (++tries > 50000000L) break;      // escape hatch: never hang
    }
    __threadfence();                       // acquire: discard stale cached lines
  }
  __syncthreads();
}

// ---- X GEMM tile: C[row0..+127][col0..+63] of gather(embed,tokens)@[W_ioux|W_fx] ----
__device__ void gemm_x_tile(Smem& sm, int row0, int col0,
    const int* __restrict__ tokens, const float* __restrict__ embed,
    const float* __restrict__ W_ioux, const float* __restrict__ W_fx,
    const float* __restrict__ b_ioux, const float* __restrict__ b_fx,
    float* __restrict__ xiou, float* __restrict__ fxo)
{
  const int tid = threadIdx.x;
  __syncthreads();
  if (tid < 128) {
    int r = row0 + tid;
    sm.g.toks[tid] = (r < NN) ? tokens[r] : 0;
  }
  float acc[8][4] = {};
  const int trow = (tid >> 4) * 8;
  const int tcol = (tid & 15) * 4;
  const int ar  = tid >> 1;
  const int akh = (tid & 1) * 8;
  const int bk  = tid >> 4;
  const int bc  = (tid & 15) * 4;
  for (int k0 = 0; k0 < 300; k0 += 16) {
    __syncthreads();
    {
      float4 v0 = {0,0,0,0}, v1 = {0,0,0,0};
      const int kb = k0 + akh;
      const float* src = embed + (size_t)sm.g.toks[ar] * 300;
      if (kb + 3 < 300) v0 = *(const float4*)(src + kb);
      if (kb + 7 < 300) v1 = *(const float4*)(src + kb + 4);
      sm.g.As[akh+0][ar] = v0.x; sm.g.As[akh+1][ar] = v0.y; sm.g.As[akh+2][ar] = v0.z; sm.g.As[akh+3][ar] = v0.w;
      sm.g.As[akh+4][ar] = v1.x; sm.g.As[akh+5][ar] = v1.y; sm.g.As[akh+6][ar] = v1.z; sm.g.As[akh+7][ar] = v1.w;
    }
    {
      float4 v = {0,0,0,0};
      const int k = k0 + bk;
      const int col = col0 + bc;
      if (k < 300) {
        if (col < 900)        v = *(const float4*)(W_ioux + (size_t)k * 900 + col);
        else if (col < 1200)  v = *(const float4*)(W_fx + (size_t)k * 300 + (col - 900));
      }
      *(float4*)&sm.g.Bs[bk][bc] = v;
    }
    __syncthreads();
#pragma unroll
    for (int kk = 0; kk < 16; ++kk) {
      float4 a0 = *(const float4*)&sm.g.As[kk][trow];
      float4 a1 = *(const float4*)&sm.g.As[kk][trow + 4];
      float4 b  = *(const float4*)&sm.g.Bs[kk][tcol];
      float av[8] = {a0.x,a0.y,a0.z,a0.w,a1.x,a1.y,a1.z,a1.w};
      float bv[4] = {b.x,b.y,b.z,b.w};
#pragma unroll
      for (int i = 0; i < 8; ++i)
#pragma unroll
        for (int j = 0; j < 4; ++j) acc[i][j] += av[i] * bv[j];
    }
  }
#pragma unroll
  for (int i = 0; i < 8; ++i) {
    const int grow = row0 + trow + i;
    if (grow >= NN) continue;
#pragma unroll
    for (int j = 0; j < 4; ++j) {
      const int col = col0 + tcol + j;
      float v = acc[i][j];
      if (col < 900)                    xiou[(size_t)grow*900 + col] = v + b_ioux[col];
      else if (col < 1200 && grow < NI) fxo[(size_t)grow*300 + (col-900)] = v + b_fx[col-900];
    }
  }
}

// ---- iou GEMM tile: ioubuf[r][c] = hsb[start+r]@W_iouh + xiou[start+r] + b_iouh ----
__device__ void gemm_iou_tile(Smem& sm, int row0, int col0, int M, int start,
    const float* __restrict__ hsb, const float* __restrict__ xiou,
    const float* __restrict__ W_iouh, const float* __restrict__ b_iouh,
    float* __restrict__ ioubuf)
{
  const int tid = threadIdx.x;
  float acc[8][4] = {};
  const int trow = (tid >> 4) * 8;
  const int tcol = (tid & 15) * 4;
  const int ar  = tid >> 1;
  const int akh = (tid & 1) * 8;
  const int bk  = tid >> 4;
  const int bc  = (tid & 15) * 4;
  for (int k0 = 0; k0 < 300; k0 += 16) {
    __syncthreads();
    {
      float4 v0 = {0,0,0,0}, v1 = {0,0,0,0};
      const int grow = row0 + ar;
      const int kb = k0 + akh;
      if (grow < M) {
        const float* src = hsb + (size_t)(start + grow) * 300;
        if (kb + 3 < 300) v0 = *(const float4*)(src + kb);
        if (kb + 7 < 300) v1 = *(const float4*)(src + kb + 4);
      }
      sm.g.As[akh+0][ar] = v0.x; sm.g.As[akh+1][ar] = v0.y; sm.g.As[akh+2][ar] = v0.z; sm.g.As[akh+3][ar] = v0.w;
      sm.g.As[akh+4][ar] = v1.x; sm.g.As[akh+5][ar] = v1.y; sm.g.As[akh+6][ar] = v1.z; sm.g.As[akh+7][ar] = v1.w;
    }
    {
      float4 v = {0,0,0,0};
      const int k = k0 + bk;
      const int col = col0 + bc;
      if (k < 300 && col < 900) v = *(const float4*)(W_iouh + (size_t)k * 900 + col);
      *(float4*)&sm.g.Bs[bk][bc] = v;
    }
    __syncthreads();
#pragma unroll
    for (int kk = 0; kk < 16; ++kk) {
      float4 a0 = *(const float4*)&sm.g.As[kk][trow];
      float4 a1 = *(const float4*)&sm.g.As[kk][trow + 4];
      float4 b  = *(const float4*)&sm.g.Bs[kk][tcol];
      float av[8] = {a0.x,a0.y,a0.z,a0.w,a1.x,a1.y,a1.z,a1.w};
      float bv[4] = {b.x,b.y,b.z,b.w};
#pragma unroll
      for (int i = 0; i < 8; ++i)
#pragma unroll
        for (int j = 0; j < 4; ++j) acc[i][j] += av[i] * bv[j];
    }
  }
#pragma unroll
  for (int i = 0; i < 8; ++i) {
    const int grow = row0 + trow + i;
    if (grow >= M) continue;
#pragma unroll
    for (int j = 0; j < 4; ++j) {
      const int col = col0 + tcol + j;
      if (col < 900)
        ioubuf[(size_t)grow*900 + col] = acc[i][j] + xiou[(size_t)(start+grow)*900 + col] + b_iouh[col];
    }
  }
}

// ---- W_fh GEMM tile with fused f-gate + fc reduction (thread's 8 rows = one parent) ----
__device__ void gemm_fcb_tile(Smem& sm, int row0, int col0, int M, int pstart,
    const float* __restrict__ h_cur, const float* __restrict__ c_cur,
    const float* __restrict__ W_fh, const float* __restrict__ b_fh,
    const float* __restrict__ fxo, float* __restrict__ fcb)
{
  const int tid = threadIdx.x;
  float acc[8][4] = {};
  const int trow = (tid >> 4) * 8;
  const int tcol = (tid & 15) * 4;
  const int ar  = tid >> 1;
  const int akh = (tid & 1) * 8;
  const int bk  = tid >> 4;
  const int bc  = (tid & 15) * 4;
  for (int k0 = 0; k0 < 300; k0 += 16) {
    __syncthreads();
    {
      float4 v0 = {0,0,0,0}, v1 = {0,0,0,0};
      const int grow = row0 + ar;
      const int kb = k0 + akh;
      if (grow < M) {
        const float* src = h_cur + (size_t)grow * 300;
        if (kb + 3 < 300) v0 = *(const float4*)(src + kb);
        if (kb + 7 < 300) v1 = *(const float4*)(src + kb + 4);
      }
      sm.g.As[akh+0][ar] = v0.x; sm.g.As[akh+1][ar] = v0.y; sm.g.As[akh+2][ar] = v0.z; sm.g.As[akh+3][ar] = v0.w;
      sm.g.As[akh+4][ar] = v1.x; sm.g.As[akh+5][ar] = v1.y; sm.g.As[akh+6][ar] = v1.z; sm.g.As[akh+7][ar] = v1.w;
    }
    {
      float4 v = {0,0,0,0};
      const int k = k0 + bk;
      const int col = col0 + bc;
      if (k < 300 && col < 300) v = *(const float4*)(W_fh + (size_t)k * 300 + col);
      *(float4*)&sm.g.Bs[bk][bc] = v;
    }
    __syncthreads();
#pragma unroll
    for (int kk = 0; kk < 16; ++kk) {
      float4 a0 = *(const float4*)&sm.g.As[kk][trow];
      float4 a1 = *(const float4*)&sm.g.As[kk][trow + 4];
      float4 b  = *(const float4*)&sm.g.Bs[kk][tcol];
      float av[8] = {a0.x,a0.y,a0.z,a0.w,a1.x,a1.y,a1.z,a1.w};
      float bv[4] = {b.x,b.y,b.z,b.w};
#pragma unroll
      for (int i = 0; i < 8; ++i)
#pragma unroll
        for (int j = 0; j < 4; ++j) acc[i][j] += av[i] * bv[j];
    }
  }
  const int r0 = row0 + trow;
  if (r0 < M) {
    const int p = pstart + (r0 >> 3);
#pragma unroll
    for (int j = 0; j < 4; ++j) {
      const int col = col0 + tcol + j;
      if (col >= 300) continue;
      const float add = b_fh[col] + fxo[(size_t)p*300 + col];
      float fc = 0.f;
#pragma unroll
      for (int i = 0; i < 8; ++i)
        fc += sigm(acc[i][j] + add) * c_cur[(size_t)(r0 + i)*300 + col];
      fcb[(size_t)p*300 + col] = fc;
    }
  }
}

// ---- gates + h-sum for one parent group ----
__device__ void gates_unit(int vb, int pstart, int cstart, int leaf,
    const float* __restrict__ xiou, const float* __restrict__ ioubuf,
    const float* __restrict__ b_iouh, const float* __restrict__ fcb,
    float* __restrict__ h_cur, float* __restrict__ c_cur, float* __restrict__ hsb)
{
  const int p = pstart + vb;
  for (int j = threadIdx.x; j < 300; j += 256) {
    float hsum = 0.f;
#pragma unroll
    for (int k = 0; k < 8; ++k) {
      const int rel = vb * 8 + k;
      float iv, ov, uv;
      if (leaf) {
        const float* x = xiou + (size_t)(cstart + rel) * 900;
        iv = x[j] + b_iouh[j];
        ov = x[300 + j] + b_iouh[300 + j];
        uv = x[600 + j] + b_iouh[600 + j];
      } else {
        const float* x = ioubuf + (size_t)rel * 900;
        iv = x[j]; ov = x[300 + j]; uv = x[600 + j];
      }
      float cc = sigm(iv) * tanhf(uv);
      if (!leaf) cc += fcb[(size_t)(cstart + rel) * 300 + j];
      float hh = sigm(ov) * tanhf(cc);
      c_cur[(size_t)rel * 300 + j] = cc;
      h_cur[(size_t)rel * 300 + j] = hh;
      hsum += hh;
    }
    hsb[(size_t)p * 300 + j] = hsum;
  }
}

// ---- per-node for nodes 1..8 (parent = root); atomics into root accumulators ----
__device__ void node_unit(Smem& sm, int node,
    const float* __restrict__ xiou, const float* __restrict__ fxo,
    const float* __restrict__ W_iouh, const float* __restrict__ b_iouh,
    const float* __restrict__ W_fh, const float* __restrict__ b_fh,
    float* __restrict__ hsb, float* __restrict__ fcb)
{
  const int tid = threadIdx.x;
  __syncthreads();
  for (int j = tid; j < 300; j += 256) sm.n.hs[j] = hsb[(size_t)node*300 + j];
  __syncthreads();
  for (int j = tid; j < 900; j += 256) {
    float acc = xiou[(size_t)node*900 + j] + b_iouh[j];
    for (int k = 0; k < 300; ++k) acc += sm.n.hs[k] * W_iouh[k*900 + j];
    sm.n.siou[j] = acc;
  }
  __syncthreads();
  for (int j = tid; j < 300; j += 256) {
    float cc = sigm(sm.n.siou[j]) * tanhf(sm.n.siou[600 + j]) + fcb[(size_t)node*300 + j];
    sm.n.sc[j] = cc;
    sm.n.sh[j] = sigm(sm.n.siou[300 + j]) * tanhf(cc);
  }
  __syncthreads();
  for (int j = tid; j < 300; j += 256) {
    float acc = b_fh[j] + fxo[j];   // parent is root: fxo row 0
    for (int k = 0; k < 300; ++k) acc += sm.n.sh[k] * W_fh[k*300 + j];
    float f = sigm(acc);
    atomicAdd(&hsb[j], sm.n.sh[j]);
    atomicAdd(&fcb[j], f * sm.n.sc[j]);
  }
}

// ---- root: gates + W_lin head straight to d_out ----
__device__ void root_unit(Smem& sm,
    const float* __restrict__ xiou,
    const float* __restrict__ W_iouh, const float* __restrict__ b_iouh,
    const float* __restrict__ hsb, const float* __restrict__ fcb,
    const float* __restrict__ W_lin, const float* __restrict__ b_lin,
    float* __restrict__ out)
{
  const int tid = threadIdx.x;
  __syncthreads();
  for (int j = tid; j < 300; j += 256) sm.n.hs[j] = hsb[j];
  __syncthreads();
  for (int j = tid; j < 900; j += 256) {
    float acc = xiou[j] + b_iouh[j];
    for (int k = 0; k < 300; ++k) acc += sm.n.hs[k] * W_iouh[k*900 + j];
    sm.n.siou[j] = acc;
  }
  __syncthreads();
  for (int j = tid; j < 300; j += 256) {
    float cc = sigm(sm.n.siou[j]) * tanhf(sm.n.siou[600 + j]) + fcb[j];
    sm.n.sc[j] = cc;
    sm.n.sh[j] = sigm(sm.n.siou[300 + j]) * tanhf(cc);
  }
  __syncthreads();
  for (int j = tid; j < 42; j += 256) {
    float acc = b_lin[j];
    for (int k = 0; k < 300; ++k) acc += sm.n.sc[k] * W_lin[k*42 + j];
    out[j] = acc;
  }
  for (int j = tid; j < 300; j += 256) out[42 + j] = sm.n.sh[j];
}

__global__ __launch_bounds__(256, 4) void mega(
    const int* __restrict__ tokens, const float* __restrict__ embed,
    const float* __restrict__ W_ioux, const float* __restrict__ b_ioux,
    const float* __restrict__ W_iouh, const float* __restrict__ b_iouh,
    const float* __restrict__ W_fx, const float* __restrict__ b_fx,
    const float* __restrict__ W_fh, const float* __restrict__ b_fh,
    const float* __restrict__ W_lin, const float* __restrict__ b_lin,
    float* __restrict__ out,
    float* xiou, float* fxo, float* hsb, float* fcb,
    float* h_cur, float* c_cur, float* ioubuf, unsigned* bar)
{
  __shared__ Smem sm;
  const int bid = blockIdx.x;

  // P0: X GEMM — 703 tiles, exactly one per block
  {
    const int ty = bid / 19, tx = bid % 19;
    const int row0 = ty * 128, col0 = tx * 64;
    if (!(col0 >= 960 && row0 >= 640))
      gemm_x_tile(sm, row0, col0, tokens, embed, W_ioux, W_fx, b_ioux, b_fx, xiou, fxo);
  }
  gsync(bar, 0);
  // P1: leaf gates (parents 73..584)
  if (bid < 512) gates_unit(bid, 73, 585, 1, xiou, nullptr, b_iouh, nullptr, h_cur, c_cur, hsb);
  gsync(bar, 1);
  // P2: fcb leaf (M=4096 -> 32x5 tiles)
  if (bid < 160) gemm_fcb_tile(sm, (bid/5)*128, (bid%5)*64, 4096, 73, h_cur, c_cur, W_fh, b_fh, fxo, fcb);
  gsync(bar, 2);
  // P3: iou 512 (4x15 tiles)
  if (bid < 60) gemm_iou_tile(sm, (bid/15)*128, (bid%15)*64, 512, 73, hsb, xiou, W_iouh, b_iouh, ioubuf);
  gsync(bar, 3);
  // P4: gates 512 (parents 9..72)
  if (bid < 64) gates_unit(bid, 9, 73, 0, nullptr, ioubuf, b_iouh, fcb, h_cur, c_cur, hsb);
  gsync(bar, 4);
  // P5: fcb 512 (4x5 tiles)
  if (bid < 20) gemm_fcb_tile(sm, (bid/5)*128, (bid%5)*64, 512, 9, h_cur, c_cur, W_fh, b_fh, fxo, fcb);
  gsync(bar, 5);
  // P6: iou 64 (1x15 tiles)
  if (bid < 15) gemm_iou_tile(sm, 0, bid*64, 64, 9, hsb, xiou, W_iouh, b_iouh, ioubuf);
  gsync(bar, 6);
  // P7: gates 64 (parents 1..8)
  if (bid < 8) gates_unit(bid, 1, 9, 0, nullptr, ioubuf, b_iouh, fcb, h_cur, c_cur, hsb);
  gsync(bar, 7);
  // P8: fcb 64 (1x5 tiles)
  if (bid < 5) gemm_fcb_tile(sm, 0, bid*64, 64, 1, h_cur, c_cur, W_fh, b_fh, fxo, fcb);
  gsync(bar, 8);
  // P9: nodes 1..8
  if (bid < 8) node_unit(sm, 1 + bid, xiou, fxo, W_iouh, b_iouh, W_fh, b_fh, hsb, fcb);
  gsync(bar, 9);
  // P10: root
  if (bid == 0) root_unit(sm, xiou, W_iouh, b_iouh, hsb, fcb, W_lin, b_lin, out);
}

extern "C" void kernel_launch(void* const* d_in, const int* in_sizes, int n_in,
                              void* d_out, int out_size, void* d_ws, size_t ws_size,
                              hipStream_t stream) {
  const int* tokens   = (const int*)d_in[0];
  const float* embed  = (const float*)d_in[3];
  const float* W_ioux = (const float*)d_in[4];
  const float* b_ioux = (const float*)d_in[5];
  const float* W_iouh = (const float*)d_in[6];
  const float* b_iouh = (const float*)d_in[7];
  const float* W_fx   = (const float*)d_in[8];
  const float* b_fx   = (const float*)d_in[9];
  const float* W_fh   = (const float*)d_in[10];
  const float* b_fh   = (const float*)d_in[11];
  const float* W_lin  = (const float*)d_in[12];
  const float* b_lin  = (const float*)d_in[13];
  float* out = (float*)d_out;

  float* ws     = (float*)d_ws;
  float* xiou   = ws;                                  // NN*900
  float* fxo    = xiou   + (size_t)NN * 900;           // NI*300
  float* hsb    = fxo    + (size_t)NI * 300;           // NI*300
  float* fcb    = hsb    + (size_t)NI * 300;           // NI*300
  float* h_cur  = fcb    + (size_t)NI * 300;           // 4096*300
  float* c_cur  = h_cur  + (size_t)4096 * 300;         // 4096*300
  float* ioubuf = c_cur  + (size_t)4096 * 300;         // 512*900
  unsigned* bar = (unsigned*)(ioubuf + (size_t)512 * 900);  // 16 counters

  hipMemsetAsync(bar, 0, 16 * sizeof(unsigned), stream);
  hipMemsetAsync(hsb, 0, 300 * sizeof(float), stream);   // root accumulators
  hipMemsetAsync(fcb, 0, 300 * sizeof(float), stream);

  mega<<<GRID, 256, 0, stream>>>(tokens, embed, W_ioux, b_ioux, W_iouh, b_iouh,
      W_fx, b_fx, W_fh, b_fh, W_lin, b_lin, out,
      xiou, fxo, hsb, fcb, h_cur, c_cur, ioubuf, bar);
}

// Round 8
// 593.255 us; speedup vs baseline: 1.8575x; 1.8575x over previous
//
#include <hip/hip_runtime.h>

#define NN 4681        // total nodes
#define NI 585         // internal (parent) nodes
#define GRID 703

__device__ __forceinline__ float sigm(float x) { return 1.f / (1.f + expf(-x)); }

struct Smem {
  union {
    struct { float As[16][132]; float Bs[16][68]; int toks[128]; } g;
    struct { float hs[300]; float siou[900]; float sc[300]; float sh[300]; } n;
  };
};

// ---------------- grid barrier ----------------
// arrivals: fire-and-forget atomicAdd into 8 XCD-spread lines (memory-side atomics).
// block 0 aggregates; everyone else polls a READ-ONLY flag line. No RMW/poll collision.
__device__ __forceinline__ void gbar(unsigned* cnt, unsigned* flag, int k, int bid) {
  __syncthreads();
  if (threadIdx.x == 0) {
    __threadfence();   // release: data at coherence point before arrival visible
    __hip_atomic_fetch_add(&cnt[k*256 + (bid&7)*32], 1u,
                           __ATOMIC_RELAXED, __HIP_MEMORY_SCOPE_AGENT);
    if (bid == 0) {
      long tries = 0;
      for (;;) {
        unsigned s = 0;
#pragma unroll
        for (int x = 0; x < 8; ++x)
          s += __hip_atomic_load(&cnt[k*256 + x*32], __ATOMIC_RELAXED, __HIP_MEMORY_SCOPE_AGENT);
        if (s >= (unsigned)GRID) break;
        __builtin_amdgcn_s_sleep(1);
        if (++tries > 2000000L) break;   // escape hatch
      }
      __hip_atomic_store(&flag[k*32], 1u, __ATOMIC_RELEASE, __HIP_MEMORY_SCOPE_AGENT);
    } else {
      long tries = 0;
      while (__hip_atomic_load(&flag[k*32], __ATOMIC_ACQUIRE, __HIP_MEMORY_SCOPE_AGENT) == 0u) {
        __builtin_amdgcn_s_sleep(16);
        if (++tries > 2000000L) break;
      }
    }
    __threadfence();   // acquire: discard stale cached lines
  }
  __syncthreads();
}

// dead block: arrive at all remaining barriers, then caller returns
__device__ __forceinline__ void arrive_rest(unsigned* cnt, int kfrom, int bid) {
  __syncthreads();
  if (threadIdx.x == 0) {
    __threadfence();
    for (int k = kfrom; k < 8; ++k)
      __hip_atomic_fetch_add(&cnt[k*256 + (bid&7)*32], 1u,
                             __ATOMIC_RELAXED, __HIP_MEMORY_SCOPE_AGENT);
  }
}

// ---------------- P0: fused X-GEMM (+leaf gates) ----------------
// Columns staged as quads per j: (W_ioux[j], W_ioux[300+j], W_ioux[600+j], W_fx[j]).
// LEAF tiles: 3 cols only, gates+h-sum in epilogue (no xiou write).
// Internal tiles: 4 cols, write xiou triplets + fxo.
template<bool LEAF>
__device__ void fx_tile(Smem& sm, int row0, int j0,
    const int* __restrict__ tokens, const float* __restrict__ embed,
    const float* __restrict__ W_ioux, const float* __restrict__ W_fx,
    const float* __restrict__ b_ioux, const float* __restrict__ b_fx,
    const float* __restrict__ b_iouh,
    float* __restrict__ xiou, float* __restrict__ fxo,
    float* __restrict__ h_cur, float* __restrict__ c_cur, float* __restrict__ hsb)
{
  const int tid = threadIdx.x;
  if (tid < 128) {
    int r = row0 + tid;
    sm.g.toks[tid] = (r < NN) ? tokens[r] : 0;
  }
  float acc[8][4] = {};
  const int trow = (tid >> 4) * 8;
  const int jl   = tid & 15;
  const int j    = j0 + jl;
  const int ar   = tid >> 1;
  const int akh  = (tid & 1) * 8;
  const int bk   = tid >> 4;

  for (int k0 = 0; k0 < 300; k0 += 16) {
    __syncthreads();
    {
      float4 v0 = {0,0,0,0}, v1 = {0,0,0,0};
      const int kb = k0 + akh;
      const float* src = embed + (size_t)sm.g.toks[ar] * 300;
      if (kb + 3 < 300) v0 = *(const float4*)(src + kb);
      if (kb + 7 < 300) v1 = *(const float4*)(src + kb + 4);
      sm.g.As[akh+0][ar] = v0.x; sm.g.As[akh+1][ar] = v0.y; sm.g.As[akh+2][ar] = v0.z; sm.g.As[akh+3][ar] = v0.w;
      sm.g.As[akh+4][ar] = v1.x; sm.g.As[akh+5][ar] = v1.y; sm.g.As[akh+6][ar] = v1.z; sm.g.As[akh+7][ar] = v1.w;
    }
    {
      float4 w = {0,0,0,0};
      const int k = k0 + bk;
      if (k < 300 && j < 300) {
        w.x = W_ioux[(size_t)k*900 + j];
        w.y = W_ioux[(size_t)k*900 + 300 + j];
        w.z = W_ioux[(size_t)k*900 + 600 + j];
        if (!LEAF) w.w = W_fx[(size_t)k*300 + j];
      }
      *(float4*)&sm.g.Bs[bk][4*jl] = w;
    }
    __syncthreads();
#pragma unroll
    for (int kk = 0; kk < 16; ++kk) {
      float4 a0 = *(const float4*)&sm.g.As[kk][trow];
      float4 a1 = *(const float4*)&sm.g.As[kk][trow + 4];
      float4 b  = *(const float4*)&sm.g.Bs[kk][4*jl];
      float av[8] = {a0.x,a0.y,a0.z,a0.w,a1.x,a1.y,a1.z,a1.w};
#pragma unroll
      for (int i = 0; i < 8; ++i) {
        acc[i][0] += av[i] * b.x;
        acc[i][1] += av[i] * b.y;
        acc[i][2] += av[i] * b.z;
        if (!LEAF) acc[i][3] += av[i] * b.w;
      }
    }
  }
  if (j >= 300) return;
  const int r0g = row0 + trow;
  if (LEAF) {
    const float bi = b_ioux[j] + b_iouh[j];
    const float bo = b_ioux[300+j] + b_iouh[300+j];
    const float bu = b_ioux[600+j] + b_iouh[600+j];
    float hsum = 0.f;
#pragma unroll
    for (int i = 0; i < 8; ++i) {
      float iv = acc[i][0] + bi;
      float ov = acc[i][1] + bo;
      float uv = acc[i][2] + bu;
      float cc = sigm(iv) * tanhf(uv);
      float hh = sigm(ov) * tanhf(cc);
      const int rel = r0g - 585 + i;
      c_cur[(size_t)rel*300 + j] = cc;
      h_cur[(size_t)rel*300 + j] = hh;
      hsum += hh;
    }
    hsb[(size_t)(73 + ((r0g - 585) >> 3))*300 + j] = hsum;
  } else {
#pragma unroll
    for (int i = 0; i < 8; ++i) {
      const int grow = r0g + i;
      if (grow < NI) {
        xiou[(size_t)grow*900 + j]        = acc[i][0] + b_ioux[j];
        xiou[(size_t)grow*900 + 300 + j]  = acc[i][1] + b_ioux[300+j];
        xiou[(size_t)grow*900 + 600 + j]  = acc[i][2] + b_ioux[600+j];
        fxo[(size_t)grow*300 + j]         = acc[i][3] + b_fx[j];
      }
    }
  }
}

// ---------------- fused iou-GEMM + gates + h-sum for internal levels ----------------
// A = hsb rows [start+row0 ..), B = W_iouh triplets per j. Thread's 8 rows = 1 parent group.
__device__ void ig_tile(Smem& sm, int row0, int j0, int M, int start, int pstart,
    const float* __restrict__ hsb_in, const float* __restrict__ xiou,
    const float* __restrict__ W_iouh, const float* __restrict__ b_iouh,
    const float* __restrict__ fcb,
    float* __restrict__ h_cur, float* __restrict__ c_cur, float* __restrict__ hsb_out)
{
  const int tid = threadIdx.x;
  float acc[8][3] = {};
  const int trow = (tid >> 4) * 8;
  const int jl   = tid & 15;
  const int j    = j0 + jl;
  const int ar   = tid >> 1;
  const int akh  = (tid & 1) * 8;
  const int bk   = tid >> 4;

  for (int k0 = 0; k0 < 300; k0 += 16) {
    __syncthreads();
    {
      float4 v0 = {0,0,0,0}, v1 = {0,0,0,0};
      const int grow = row0 + ar;
      const int kb = k0 + akh;
      if (grow < M) {
        const float* src = hsb_in + (size_t)(start + grow) * 300;
        if (kb + 3 < 300) v0 = *(const float4*)(src + kb);
        if (kb + 7 < 300) v1 = *(const float4*)(src + kb + 4);
      }
      sm.g.As[akh+0][ar] = v0.x; sm.g.As[akh+1][ar] = v0.y; sm.g.As[akh+2][ar] = v0.z; sm.g.As[akh+3][ar] = v0.w;
      sm.g.As[akh+4][ar] = v1.x; sm.g.As[akh+5][ar] = v1.y; sm.g.As[akh+6][ar] = v1.z; sm.g.As[akh+7][ar] = v1.w;
    }
    {
      float w0 = 0.f, w1 = 0.f, w2 = 0.f;
      const int k = k0 + bk;
      if (k < 300 && j < 300) {
        w0 = W_iouh[(size_t)k*900 + j];
        w1 = W_iouh[(size_t)k*900 + 300 + j];
        w2 = W_iouh[(size_t)k*900 + 600 + j];
      }
      sm.g.Bs[bk][3*jl+0] = w0;
      sm.g.Bs[bk][3*jl+1] = w1;
      sm.g.Bs[bk][3*jl+2] = w2;
    }
    __syncthreads();
#pragma unroll
    for (int kk = 0; kk < 16; ++kk) {
      float4 a0 = *(const float4*)&sm.g.As[kk][trow];
      float4 a1 = *(const float4*)&sm.g.As[kk][trow + 4];
      float b0 = sm.g.Bs[kk][3*jl+0];
      float b1 = sm.g.Bs[kk][3*jl+1];
      float b2 = sm.g.Bs[kk][3*jl+2];
      float av[8] = {a0.x,a0.y,a0.z,a0.w,a1.x,a1.y,a1.z,a1.w};
#pragma unroll
      for (int i = 0; i < 8; ++i) {
        acc[i][0] += av[i] * b0;
        acc[i][1] += av[i] * b1;
        acc[i][2] += av[i] * b2;
      }
    }
  }
  if (j >= 300) return;
  const int r0 = row0 + trow;
  if (r0 >= M) return;
  float hsum = 0.f;
#pragma unroll
  for (int i = 0; i < 8; ++i) {
    const int node = start + r0 + i;
    float iv = acc[i][0] + xiou[(size_t)node*900 + j]        + b_iouh[j];
    float ov = acc[i][1] + xiou[(size_t)node*900 + 300 + j]  + b_iouh[300+j];
    float uv = acc[i][2] + xiou[(size_t)node*900 + 600 + j]  + b_iouh[600+j];
    float cc = sigm(iv) * tanhf(uv) + fcb[(size_t)node*300 + j];
    float hh = sigm(ov) * tanhf(cc);
    c_cur[(size_t)(r0+i)*300 + j] = cc;
    h_cur[(size_t)(r0+i)*300 + j] = hh;
    hsum += hh;
  }
  hsb_out[(size_t)(pstart + (r0 >> 3))*300 + j] = hsum;
}

// ---------------- W_fh GEMM + fused f-gate + fc reduction ----------------
__device__ void fcb_tile(Smem& sm, int row0, int col0, int M, int pstart,
    const float* __restrict__ h_cur, const float* __restrict__ c_cur,
    const float* __restrict__ W_fh, const float* __restrict__ b_fh,
    const float* __restrict__ fxo, float* __restrict__ fcb)
{
  const int tid = threadIdx.x;
  float acc[8][4] = {};
  const int trow = (tid >> 4) * 8;
  const int tcol = (tid & 15) * 4;
  const int ar  = tid >> 1;
  const int akh = (tid & 1) * 8;
  const int bk  = tid >> 4;
  const int bc  = (tid & 15) * 4;
  for (int k0 = 0; k0 < 300; k0 += 16) {
    __syncthreads();
    {
      float4 v0 = {0,0,0,0}, v1 = {0,0,0,0};
      const int grow = row0 + ar;
      const int kb = k0 + akh;
      if (grow < M) {
        const float* src = h_cur + (size_t)grow * 300;
        if (kb + 3 < 300) v0 = *(const float4*)(src + kb);
        if (kb + 7 < 300) v1 = *(const float4*)(src + kb + 4);
      }
      sm.g.As[akh+0][ar] = v0.x; sm.g.As[akh+1][ar] = v0.y; sm.g.As[akh+2][ar] = v0.z; sm.g.As[akh+3][ar] = v0.w;
      sm.g.As[akh+4][ar] = v1.x; sm.g.As[akh+5][ar] = v1.y; sm.g.As[akh+6][ar] = v1.z; sm.g.As[akh+7][ar] = v1.w;
    }
    {
      float4 v = {0,0,0,0};
      const int k = k0 + bk;
      const int col = col0 + bc;
      if (k < 300 && col < 300) v = *(const float4*)(W_fh + (size_t)k * 300 + col);
      *(float4*)&sm.g.Bs[bk][bc] = v;
    }
    __syncthreads();
#pragma unroll
    for (int kk = 0; kk < 16; ++kk) {
      float4 a0 = *(const float4*)&sm.g.As[kk][trow];
      float4 a1 = *(const float4*)&sm.g.As[kk][trow + 4];
      float4 b  = *(const float4*)&sm.g.Bs[kk][tcol];
      float av[8] = {a0.x,a0.y,a0.z,a0.w,a1.x,a1.y,a1.z,a1.w};
      float bv[4] = {b.x,b.y,b.z,b.w};
#pragma unroll
      for (int i = 0; i < 8; ++i)
#pragma unroll
        for (int jj = 0; jj < 4; ++jj) acc[i][jj] += av[i] * bv[jj];
    }
  }
  const int r0 = row0 + trow;
  if (r0 < M) {
    const int p = pstart + (r0 >> 3);
#pragma unroll
    for (int jj = 0; jj < 4; ++jj) {
      const int col = col0 + tcol + jj;
      if (col >= 300) continue;
      const float add = b_fh[col] + fxo[(size_t)p*300 + col];
      float fc = 0.f;
#pragma unroll
      for (int i = 0; i < 8; ++i)
        fc += sigm(acc[i][jj] + add) * c_cur[(size_t)(r0 + i)*300 + col];
      fcb[(size_t)p*300 + col] = fc;
    }
  }
}

// ---------------- root: gates + W_lin head ----------------
__device__ void root_unit(Smem& sm,
    const float* __restrict__ xiou,
    const float* __restrict__ W_iouh, const float* __restrict__ b_iouh,
    const float* __restrict__ hsb, const float* __restrict__ fcb,
    const float* __restrict__ W_lin, const float* __restrict__ b_lin,
    float* __restrict__ out)
{
  const int tid = threadIdx.x;
  __syncthreads();
  for (int j = tid; j < 300; j += 256) sm.n.hs[j] = hsb[j];
  __syncthreads();
  for (int j = tid; j < 900; j += 256) {
    float acc = xiou[j] + b_iouh[j];
    for (int k = 0; k < 300; ++k) acc += sm.n.hs[k] * W_iouh[k*900 + j];
    sm.n.siou[j] = acc;
  }
  __syncthreads();
  for (int j = tid; j < 300; j += 256) {
    float cc = sigm(sm.n.siou[j]) * tanhf(sm.n.siou[600 + j]) + fcb[j];
    sm.n.sc[j] = cc;
    sm.n.sh[j] = sigm(sm.n.siou[300 + j]) * tanhf(cc);
  }
  __syncthreads();
  for (int j = tid; j < 42; j += 256) {
    float acc = b_lin[j];
    for (int k = 0; k < 300; ++k) acc += sm.n.sc[k] * W_lin[k*42 + j];
    out[j] = acc;
  }
  for (int j = tid; j < 300; j += 256) out[42 + j] = sm.n.sh[j];
}

__global__ __launch_bounds__(256, 4) void mega(
    const int* __restrict__ tokens, const float* __restrict__ embed,
    const float* __restrict__ W_ioux, const float* __restrict__ b_ioux,
    const float* __restrict__ W_iouh, const float* __restrict__ b_iouh,
    const float* __restrict__ W_fx, const float* __restrict__ b_fx,
    const float* __restrict__ W_fh, const float* __restrict__ b_fh,
    const float* __restrict__ W_lin, const float* __restrict__ b_lin,
    float* __restrict__ out,
    float* xiou, float* fxo, float* hsb, float* fcb,
    float* h_cur, float* c_cur, unsigned* cnt, unsigned* flag)
{
  __shared__ Smem sm;
  const int bid = blockIdx.x;

  // P0: fused X-GEMM (internal: xiou+fxo; leaf: gates + h,c + hsb). 37x19 tiles.
  {
    const int rt = bid / 19, jt = bid % 19;
    if (rt < 5)
      fx_tile<false>(sm, rt*128, jt*16, tokens, embed, W_ioux, W_fx, b_ioux, b_fx, b_iouh,
                     xiou, fxo, h_cur, c_cur, hsb);
    else
      fx_tile<true>(sm, 585 + (rt-5)*128, jt*16, tokens, embed, W_ioux, W_fx, b_ioux, b_fx, b_iouh,
                    xiou, fxo, h_cur, c_cur, hsb);
  }
  gbar(cnt, flag, 0, bid);
  if (bid >= 160) { arrive_rest(cnt, 1, bid); return; }

  // P1: fcb leaf (parents 73..584), 32x5 tiles
  fcb_tile(sm, (bid/5)*128, (bid%5)*64, 4096, 73, h_cur, c_cur, W_fh, b_fh, fxo, fcb);
  gbar(cnt, flag, 1, bid);
  if (bid >= 76) { arrive_rest(cnt, 2, bid); return; }

  // P2: fused iou+gates level-512 (nodes 73..584, parents 9..72), 4x19 tiles
  ig_tile(sm, (bid/19)*128, (bid%19)*16, 512, 73, 9, hsb, xiou, W_iouh, b_iouh, fcb, h_cur, c_cur, hsb);
  gbar(cnt, flag, 2, bid);
  if (bid >= 20) { arrive_rest(cnt, 3, bid); return; }

  // P3: fcb 512 (parents 9..72), 4x5 tiles
  fcb_tile(sm, (bid/5)*128, (bid%5)*64, 512, 9, h_cur, c_cur, W_fh, b_fh, fxo, fcb);
  gbar(cnt, flag, 3, bid);
  if (bid >= 19) { arrive_rest(cnt, 4, bid); return; }

  // P4: fused iou+gates level-64 (nodes 9..72, parents 1..8), 1x19 tiles
  ig_tile(sm, 0, bid*16, 64, 9, 1, hsb, xiou, W_iouh, b_iouh, fcb, h_cur, c_cur, hsb);
  gbar(cnt, flag, 4, bid);

  // P5: fcb 64 (parents 1..8), 1x5 tiles
  if (bid < 5) fcb_tile(sm, 0, bid*64, 64, 1, h_cur, c_cur, W_fh, b_fh, fxo, fcb);
  gbar(cnt, flag, 5, bid);

  // P6: fused iou+gates level-8 (nodes 1..8, parent 0), 1x19 tiles
  ig_tile(sm, 0, bid*16, 8, 1, 0, hsb, xiou, W_iouh, b_iouh, fcb, h_cur, c_cur, hsb);
  gbar(cnt, flag, 6, bid);
  if (bid >= 5) { arrive_rest(cnt, 7, bid); return; }

  // P7: fcb 8 (parent 0 = root), 1x5 tiles
  fcb_tile(sm, 0, bid*64, 8, 0, h_cur, c_cur, W_fh, b_fh, fxo, fcb);
  gbar(cnt, flag, 7, bid);
  if (bid >= 1) return;

  // P8: root
  root_unit(sm, xiou, W_iouh, b_iouh, hsb, fcb, W_lin, b_lin, out);
}

extern "C" void kernel_launch(void* const* d_in, const int* in_sizes, int n_in,
                              void* d_out, int out_size, void* d_ws, size_t ws_size,
                              hipStream_t stream) {
  const int* tokens   = (const int*)d_in[0];
  const float* embed  = (const float*)d_in[3];
  const float* W_ioux = (const float*)d_in[4];
  const float* b_ioux = (const float*)d_in[5];
  const float* W_iouh = (const float*)d_in[6];
  const float* b_iouh = (const float*)d_in[7];
  const float* W_fx   = (const float*)d_in[8];
  const float* b_fx   = (const float*)d_in[9];
  const float* W_fh   = (const float*)d_in[10];
  const float* b_fh   = (const float*)d_in[11];
  const float* W_lin  = (const float*)d_in[12];
  const float* b_lin  = (const float*)d_in[13];
  float* out = (float*)d_out;

  float* ws    = (float*)d_ws;
  float* xiou  = ws;                                 // NI*900 (internal rows only)
  float* fxo   = xiou  + (size_t)NI * 900;           // NI*300
  float* hsb   = fxo   + (size_t)NI * 300;           // NI*300
  float* fcb   = hsb   + (size_t)NI * 300;           // NI*300
  float* h_cur = fcb   + (size_t)NI * 300;           // 4096*300
  float* c_cur = h_cur + (size_t)4096 * 300;         // 4096*300
  unsigned* cnt  = (unsigned*)(c_cur + (size_t)4096 * 300);  // 8 barriers x 256 words
  unsigned* flag = cnt + 8 * 256;                            // 8 barriers x 32 words

  hipMemsetAsync(cnt, 0, (8 * 256 + 8 * 32) * sizeof(unsigned), stream);

  mega<<<GRID, 256, 0, stream>>>(tokens, embed, W_ioux, b_ioux, W_iouh, b_iouh,
      W_fx, b_fx, W_fh, b_fh, W_lin, b_lin, out,
      xiou, fxo, hsb, fcb, h_cur, c_cur, cnt, flag);
}

// Round 9
// 558.728 us; speedup vs baseline: 1.9723x; 1.0618x over previous
//
#include <hip/hip_runtime.h>

#define NN 4681        // total nodes
#define NI 585         // internal (parent) nodes

__device__ __forceinline__ float sigm(float x) { return 1.f / (1.f + expf(-x)); }

struct Smem {
  union {
    struct { float As[16][132]; float Bs[16][68]; int toks[128]; } g;
    struct { float hs[300]; float siou[900]; float sc[300]; float sh[300]; } n;
  };
};

// ---------------- fused X-GEMM (+leaf gates) ----------------
// B staged as quads per j: (W_ioux[j], W_ioux[300+j], W_ioux[600+j], W_fx[j]).
// LEAF tiles: 3 cols, gates + h/c + hsb in epilogue (no xiou traffic).
// Internal tiles: write xiou triplets + fxo.
template<bool LEAF>
__global__ __launch_bounds__(256, 4) void fx_kernel(
    const int* __restrict__ tokens, const float* __restrict__ embed,
    const float* __restrict__ W_ioux, const float* __restrict__ W_fx,
    const float* __restrict__ b_ioux, const float* __restrict__ b_fx,
    const float* __restrict__ b_iouh,
    float* __restrict__ xiou, float* __restrict__ fxo,
    float* __restrict__ h_cur, float* __restrict__ c_cur, float* __restrict__ hsb)
{
  __shared__ Smem sm;
  const int rt = blockIdx.x / 19, jt = blockIdx.x % 19;
  const int row0 = LEAF ? (585 + rt * 128) : (rt * 128);
  const int j0 = jt * 16;
  const int tid = threadIdx.x;
  if (tid < 128) {
    int r = row0 + tid;
    sm.g.toks[tid] = (r < NN) ? tokens[r] : 0;
  }
  float acc[8][4] = {};
  const int trow = (tid >> 4) * 8;
  const int jl   = tid & 15;
  const int j    = j0 + jl;
  const int ar   = tid >> 1;
  const int akh  = (tid & 1) * 8;
  const int bk   = tid >> 4;

  for (int k0 = 0; k0 < 300; k0 += 16) {
    __syncthreads();
    {
      float4 v0 = {0,0,0,0}, v1 = {0,0,0,0};
      const int kb = k0 + akh;
      const float* src = embed + (size_t)sm.g.toks[ar] * 300;
      if (kb + 3 < 300) v0 = *(const float4*)(src + kb);
      if (kb + 7 < 300) v1 = *(const float4*)(src + kb + 4);
      sm.g.As[akh+0][ar] = v0.x; sm.g.As[akh+1][ar] = v0.y; sm.g.As[akh+2][ar] = v0.z; sm.g.As[akh+3][ar] = v0.w;
      sm.g.As[akh+4][ar] = v1.x; sm.g.As[akh+5][ar] = v1.y; sm.g.As[akh+6][ar] = v1.z; sm.g.As[akh+7][ar] = v1.w;
    }
    {
      float4 w = {0,0,0,0};
      const int k = k0 + bk;
      if (k < 300 && j < 300) {
        w.x = W_ioux[(size_t)k*900 + j];
        w.y = W_ioux[(size_t)k*900 + 300 + j];
        w.z = W_ioux[(size_t)k*900 + 600 + j];
        if (!LEAF) w.w = W_fx[(size_t)k*300 + j];
      }
      *(float4*)&sm.g.Bs[bk][4*jl] = w;
    }
    __syncthreads();
#pragma unroll
    for (int kk = 0; kk < 16; ++kk) {
      float4 a0 = *(const float4*)&sm.g.As[kk][trow];
      float4 a1 = *(const float4*)&sm.g.As[kk][trow + 4];
      float4 b  = *(const float4*)&sm.g.Bs[kk][4*jl];
      float av[8] = {a0.x,a0.y,a0.z,a0.w,a1.x,a1.y,a1.z,a1.w};
#pragma unroll
      for (int i = 0; i < 8; ++i) {
        acc[i][0] += av[i] * b.x;
        acc[i][1] += av[i] * b.y;
        acc[i][2] += av[i] * b.z;
        if (!LEAF) acc[i][3] += av[i] * b.w;
      }
    }
  }
  if (j >= 300) return;
  const int r0g = row0 + trow;
  if (LEAF) {
    const float bi = b_ioux[j] + b_iouh[j];
    const float bo = b_ioux[300+j] + b_iouh[300+j];
    const float bu = b_ioux[600+j] + b_iouh[600+j];
    float hsum = 0.f;
#pragma unroll
    for (int i = 0; i < 8; ++i) {
      float iv = acc[i][0] + bi;
      float ov = acc[i][1] + bo;
      float uv = acc[i][2] + bu;
      float cc = sigm(iv) * tanhf(uv);
      float hh = sigm(ov) * tanhf(cc);
      const int rel = r0g - 585 + i;
      c_cur[(size_t)rel*300 + j] = cc;
      h_cur[(size_t)rel*300 + j] = hh;
      hsum += hh;
    }
    hsb[(size_t)(73 + ((r0g - 585) >> 3))*300 + j] = hsum;
  } else {
#pragma unroll
    for (int i = 0; i < 8; ++i) {
      const int grow = r0g + i;
      if (grow < NI) {
        xiou[(size_t)grow*900 + j]        = acc[i][0] + b_ioux[j];
        xiou[(size_t)grow*900 + 300 + j]  = acc[i][1] + b_ioux[300+j];
        xiou[(size_t)grow*900 + 600 + j]  = acc[i][2] + b_ioux[600+j];
        fxo[(size_t)grow*300 + j]         = acc[i][3] + b_fx[j];
      }
    }
  }
}

// ---------------- fused iou-GEMM + gates + h-sum ----------------
__global__ __launch_bounds__(256, 4) void ig_kernel(
    int M, int start, int pstart,
    const float* __restrict__ hsb_in, const float* __restrict__ xiou,
    const float* __restrict__ W_iouh, const float* __restrict__ b_iouh,
    const float* __restrict__ fcb,
    float* __restrict__ h_cur, float* __restrict__ c_cur, float* __restrict__ hsb_out)
{
  __shared__ Smem sm;
  const int nj = 19;
  const int row0 = (blockIdx.x / nj) * 128;
  const int j0 = (blockIdx.x % nj) * 16;
  const int tid = threadIdx.x;
  float acc[8][3] = {};
  const int trow = (tid >> 4) * 8;
  const int jl   = tid & 15;
  const int j    = j0 + jl;
  const int ar   = tid >> 1;
  const int akh  = (tid & 1) * 8;
  const int bk   = tid >> 4;

  for (int k0 = 0; k0 < 300; k0 += 16) {
    __syncthreads();
    {
      float4 v0 = {0,0,0,0}, v1 = {0,0,0,0};
      const int grow = row0 + ar;
      const int kb = k0 + akh;
      if (grow < M) {
        const float* src = hsb_in + (size_t)(start + grow) * 300;
        if (kb + 3 < 300) v0 = *(const float4*)(src + kb);
        if (kb + 7 < 300) v1 = *(const float4*)(src + kb + 4);
      }
      sm.g.As[akh+0][ar] = v0.x; sm.g.As[akh+1][ar] = v0.y; sm.g.As[akh+2][ar] = v0.z; sm.g.As[akh+3][ar] = v0.w;
      sm.g.As[akh+4][ar] = v1.x; sm.g.As[akh+5][ar] = v1.y; sm.g.As[akh+6][ar] = v1.z; sm.g.As[akh+7][ar] = v1.w;
    }
    {
      float w0 = 0.f, w1 = 0.f, w2 = 0.f;
      const int k = k0 + bk;
      if (k < 300 && j < 300) {
        w0 = W_iouh[(size_t)k*900 + j];
        w1 = W_iouh[(size_t)k*900 + 300 + j];
        w2 = W_iouh[(size_t)k*900 + 600 + j];
      }
      sm.g.Bs[bk][3*jl+0] = w0;
      sm.g.Bs[bk][3*jl+1] = w1;
      sm.g.Bs[bk][3*jl+2] = w2;
    }
    __syncthreads();
#pragma unroll
    for (int kk = 0; kk < 16; ++kk) {
      float4 a0 = *(const float4*)&sm.g.As[kk][trow];
      float4 a1 = *(const float4*)&sm.g.As[kk][trow + 4];
      float b0 = sm.g.Bs[kk][3*jl+0];
      float b1 = sm.g.Bs[kk][3*jl+1];
      float b2 = sm.g.Bs[kk][3*jl+2];
      float av[8] = {a0.x,a0.y,a0.z,a0.w,a1.x,a1.y,a1.z,a1.w};
#pragma unroll
      for (int i = 0; i < 8; ++i) {
        acc[i][0] += av[i] * b0;
        acc[i][1] += av[i] * b1;
        acc[i][2] += av[i] * b2;
      }
    }
  }
  if (j >= 300) return;
  const int r0 = row0 + trow;
  if (r0 >= M) return;
  float hsum = 0.f;
#pragma unroll
  for (int i = 0; i < 8; ++i) {
    const int node = start + r0 + i;
    float iv = acc[i][0] + xiou[(size_t)node*900 + j]        + b_iouh[j];
    float ov = acc[i][1] + xiou[(size_t)node*900 + 300 + j]  + b_iouh[300+j];
    float uv = acc[i][2] + xiou[(size_t)node*900 + 600 + j]  + b_iouh[600+j];
    float cc = sigm(iv) * tanhf(uv) + fcb[(size_t)node*300 + j];
    float hh = sigm(ov) * tanhf(cc);
    c_cur[(size_t)(r0+i)*300 + j] = cc;
    h_cur[(size_t)(r0+i)*300 + j] = hh;
    hsum += hh;
  }
  hsb_out[(size_t)(pstart + (r0 >> 3))*300 + j] = hsum;
}

// ---------------- W_fh GEMM + fused f-gate + fc reduction ----------------
__global__ __launch_bounds__(256, 4) void fcb_kernel(
    int M, int pstart,
    const float* __restrict__ h_cur, const float* __restrict__ c_cur,
    const float* __restrict__ W_fh, const float* __restrict__ b_fh,
    const float* __restrict__ fxo, float* __restrict__ fcb)
{
  __shared__ Smem sm;
  const int row0 = (blockIdx.x / 5) * 128;
  const int col0 = (blockIdx.x % 5) * 64;
  const int tid = threadIdx.x;
  float acc[8][4] = {};
  const int trow = (tid >> 4) * 8;
  const int tcol = (tid & 15) * 4;
  const int ar  = tid >> 1;
  const int akh = (tid & 1) * 8;
  const int bk  = tid >> 4;
  const int bc  = (tid & 15) * 4;
  for (int k0 = 0; k0 < 300; k0 += 16) {
    __syncthreads();
    {
      float4 v0 = {0,0,0,0}, v1 = {0,0,0,0};
      const int grow = row0 + ar;
      const int kb = k0 + akh;
      if (grow < M) {
        const float* src = h_cur + (size_t)grow * 300;
        if (kb + 3 < 300) v0 = *(const float4*)(src + kb);
        if (kb + 7 < 300) v1 = *(const float4*)(src + kb + 4);
      }
      sm.g.As[akh+0][ar] = v0.x; sm.g.As[akh+1][ar] = v0.y; sm.g.As[akh+2][ar] = v0.z; sm.g.As[akh+3][ar] = v0.w;
      sm.g.As[akh+4][ar] = v1.x; sm.g.As[akh+5][ar] = v1.y; sm.g.As[akh+6][ar] = v1.z; sm.g.As[akh+7][ar] = v1.w;
    }
    {
      float4 v = {0,0,0,0};
      const int k = k0 + bk;
      const int col = col0 + bc;
      if (k < 300 && col < 300) v = *(const float4*)(W_fh + (size_t)k * 300 + col);
      *(float4*)&sm.g.Bs[bk][bc] = v;
    }
    __syncthreads();
#pragma unroll
    for (int kk = 0; kk < 16; ++kk) {
      float4 a0 = *(const float4*)&sm.g.As[kk][trow];
      float4 a1 = *(const float4*)&sm.g.As[kk][trow + 4];
      float4 b  = *(const float4*)&sm.g.Bs[kk][tcol];
      float av[8] = {a0.x,a0.y,a0.z,a0.w,a1.x,a1.y,a1.z,a1.w};
      float bv[4] = {b.x,b.y,b.z,b.w};
#pragma unroll
      for (int i = 0; i < 8; ++i)
#pragma unroll
        for (int jj = 0; jj < 4; ++jj) acc[i][jj] += av[i] * bv[jj];
    }
  }
  const int r0 = row0 + trow;
  if (r0 < M) {
    const int p = pstart + (r0 >> 3);
#pragma unroll
    for (int jj = 0; jj < 4; ++jj) {
      const int col = col0 + tcol + jj;
      if (col >= 300) continue;
      const float add = b_fh[col] + fxo[(size_t)p*300 + col];
      float fc = 0.f;
#pragma unroll
      for (int i = 0; i < 8; ++i)
        fc += sigm(acc[i][jj] + add) * c_cur[(size_t)(r0 + i)*300 + col];
      fcb[(size_t)p*300 + col] = fc;
    }
  }
}

// ---------------- root: gates + W_lin head ----------------
__global__ __launch_bounds__(256) void root_kernel(
    const float* __restrict__ xiou,
    const float* __restrict__ W_iouh, const float* __restrict__ b_iouh,
    const float* __restrict__ hsb, const float* __restrict__ fcb,
    const float* __restrict__ W_lin, const float* __restrict__ b_lin,
    float* __restrict__ out)
{
  __shared__ Smem sm;
  const int tid = threadIdx.x;
  for (int j = tid; j < 300; j += 256) sm.n.hs[j] = hsb[j];
  __syncthreads();
  for (int j = tid; j < 900; j += 256) {
    float acc = xiou[j] + b_iouh[j];
    for (int k = 0; k < 300; ++k) acc += sm.n.hs[k] * W_iouh[k*900 + j];
    sm.n.siou[j] = acc;
  }
  __syncthreads();
  for (int j = tid; j < 300; j += 256) {
    float cc = sigm(sm.n.siou[j]) * tanhf(sm.n.siou[600 + j]) + fcb[j];
    sm.n.sc[j] = cc;
    sm.n.sh[j] = sigm(sm.n.siou[300 + j]) * tanhf(cc);
  }
  __syncthreads();
  for (int j = tid; j < 42; j += 256) {
    float acc = b_lin[j];
    for (int k = 0; k < 300; ++k) acc += sm.n.sc[k] * W_lin[k*42 + j];
    out[j] = acc;
  }
  for (int j = tid; j < 300; j += 256) out[42 + j] = sm.n.sh[j];
}

extern "C" void kernel_launch(void* const* d_in, const int* in_sizes, int n_in,
                              void* d_out, int out_size, void* d_ws, size_t ws_size,
                              hipStream_t stream) {
  const int* tokens   = (const int*)d_in[0];
  const float* embed  = (const float*)d_in[3];
  const float* W_ioux = (const float*)d_in[4];
  const float* b_ioux = (const float*)d_in[5];
  const float* W_iouh = (const float*)d_in[6];
  const float* b_iouh = (const float*)d_in[7];
  const float* W_fx   = (const float*)d_in[8];
  const float* b_fx   = (const float*)d_in[9];
  const float* W_fh   = (const float*)d_in[10];
  const float* b_fh   = (const float*)d_in[11];
  const float* W_lin  = (const float*)d_in[12];
  const float* b_lin  = (const float*)d_in[13];
  float* out = (float*)d_out;

  float* ws    = (float*)d_ws;
  float* xiou  = ws;                                 // NI*900 (internal rows only)
  float* fxo   = xiou  + (size_t)NI * 900;           // NI*300
  float* hsb   = fxo   + (size_t)NI * 300;           // NI*300
  float* fcb   = hsb   + (size_t)NI * 300;           // NI*300
  float* h_cur = fcb   + (size_t)NI * 300;           // 4096*300
  float* c_cur = h_cur + (size_t)4096 * 300;         // 4096*300

  // K0a: internal rows (xiou + fxo), 5x19 tiles
  fx_kernel<false><<<5*19, 256, 0, stream>>>(tokens, embed, W_ioux, W_fx,
      b_ioux, b_fx, b_iouh, xiou, fxo, h_cur, c_cur, hsb);
  // K0b: leaf rows (gates + h/c + hsb), 32x19 tiles
  fx_kernel<true><<<32*19, 256, 0, stream>>>(tokens, embed, W_ioux, W_fx,
      b_ioux, b_fx, b_iouh, xiou, fxo, h_cur, c_cur, hsb);
  // K1: fcb leaf (parents 73..584)
  fcb_kernel<<<32*5, 256, 0, stream>>>(4096, 73, h_cur, c_cur, W_fh, b_fh, fxo, fcb);
  // K2: ig 512 (nodes 73..584 -> parents 9..72)
  ig_kernel<<<4*19, 256, 0, stream>>>(512, 73, 9, hsb, xiou, W_iouh, b_iouh, fcb, h_cur, c_cur, hsb);
  // K3: fcb 512
  fcb_kernel<<<4*5, 256, 0, stream>>>(512, 9, h_cur, c_cur, W_fh, b_fh, fxo, fcb);
  // K4: ig 64 (nodes 9..72 -> parents 1..8)
  ig_kernel<<<19, 256, 0, stream>>>(64, 9, 1, hsb, xiou, W_iouh, b_iouh, fcb, h_cur, c_cur, hsb);
  // K5: fcb 64
  fcb_kernel<<<5, 256, 0, stream>>>(64, 1, h_cur, c_cur, W_fh, b_fh, fxo, fcb);
  // K6: ig 8 (nodes 1..8 -> parent 0)
  ig_kernel<<<19, 256, 0, stream>>>(8, 1, 0, hsb, xiou, W_iouh, b_iouh, fcb, h_cur, c_cur, hsb);
  // K7: fcb 8 (root)
  fcb_kernel<<<5, 256, 0, stream>>>(8, 0, h_cur, c_cur, W_fh, b_fh, fxo, fcb);
  // K8: root
  root_kernel<<<1, 256, 0, stream>>>(xiou, W_iouh, b_iouh, hsb, fcb, W_lin, b_lin, out);
}

// Round 10
// 402.933 us; speedup vs baseline: 2.7348x; 1.3867x over previous
//
#include <hip/hip_runtime.h>

#define NN 4681        // total nodes
#define NI 585         // internal (parent) nodes

__device__ __forceinline__ float sigm(float x) { return 1.f / (1.f + expf(-x)); }

// ---------------- merged X-GEMM: internal rows -> xiou+fxo, leaf rows -> gates+h/c+hsb ----
// 703 blocks = 37 row-tiles x 19 j-tiles. B staged as per-j quads (i,o,u[,fx]).
// Double-buffered LDS, one barrier per K-step.
__global__ __launch_bounds__(256) void fx_kernel(
    const int* __restrict__ tokens, const float* __restrict__ embed,
    const float* __restrict__ W_ioux, const float* __restrict__ W_fx,
    const float* __restrict__ b_ioux, const float* __restrict__ b_fx,
    const float* __restrict__ b_iouh,
    float* __restrict__ xiou, float* __restrict__ fxo,
    float* __restrict__ h_cur, float* __restrict__ c_cur, float* __restrict__ hsb)
{
  __shared__ float As[2][16][132];
  __shared__ float Bs[2][16][68];
  __shared__ int toks[128];
  const int tid = threadIdx.x;
  const int rt = blockIdx.x / 19, jt = blockIdx.x % 19;
  const bool leaf = (rt >= 5);
  const int row0 = leaf ? (585 + (rt - 5) * 128) : (rt * 128);
  const int j0 = jt * 16;

  if (tid < 128) toks[tid] = tokens[row0 + tid];
  __syncthreads();

  const int trow = (tid >> 4) * 8;
  const int jl   = tid & 15;
  const int j    = j0 + jl;
  const int ar   = tid >> 1;
  const int akh  = (tid & 1) * 8;
  const int bk   = tid >> 4;

  float4 a0r, a1r, wr;
  // ---- prologue: stage k0 = 0 ----
  {
    a0r = {0,0,0,0}; a1r = {0,0,0,0}; wr = {0,0,0,0};
    const float* src = embed + (size_t)toks[ar] * 300;
    a0r = *(const float4*)(src + akh);
    a1r = *(const float4*)(src + akh + 4);
    if (j < 300) {
      const float* Wp = W_ioux + (size_t)bk * 900 + j;
      wr.x = Wp[0]; wr.y = Wp[300]; wr.z = Wp[600];
      if (!leaf) wr.w = W_fx[(size_t)bk * 300 + j];
    }
    As[0][akh+0][ar] = a0r.x; As[0][akh+1][ar] = a0r.y; As[0][akh+2][ar] = a0r.z; As[0][akh+3][ar] = a0r.w;
    As[0][akh+4][ar] = a1r.x; As[0][akh+5][ar] = a1r.y; As[0][akh+6][ar] = a1r.z; As[0][akh+7][ar] = a1r.w;
    *(float4*)&Bs[0][bk][4*jl] = wr;
  }
  __syncthreads();

  float acc[8][4] = {};
  for (int t = 0; t < 19; ++t) {
    const int cur = t & 1;
    if (t < 18) {
      const int k0 = (t + 1) * 16;
      a0r = {0,0,0,0}; a1r = {0,0,0,0}; wr = {0,0,0,0};
      const int kb = k0 + akh;
      const float* src = embed + (size_t)toks[ar] * 300;
      if (kb + 3 < 300) a0r = *(const float4*)(src + kb);
      if (kb + 7 < 300) a1r = *(const float4*)(src + kb + 4);
      const int k = k0 + bk;
      if (k < 300 && j < 300) {
        const float* Wp = W_ioux + (size_t)k * 900 + j;
        wr.x = Wp[0]; wr.y = Wp[300]; wr.z = Wp[600];
        if (!leaf) wr.w = W_fx[(size_t)k * 300 + j];
      }
    }
    if (leaf) {
#pragma unroll
      for (int kk = 0; kk < 16; ++kk) {
        float4 a0 = *(const float4*)&As[cur][kk][trow];
        float4 a1 = *(const float4*)&As[cur][kk][trow + 4];
        float4 b  = *(const float4*)&Bs[cur][kk][4*jl];
        float av[8] = {a0.x,a0.y,a0.z,a0.w,a1.x,a1.y,a1.z,a1.w};
#pragma unroll
        for (int i = 0; i < 8; ++i) {
          acc[i][0] += av[i] * b.x;
          acc[i][1] += av[i] * b.y;
          acc[i][2] += av[i] * b.z;
        }
      }
    } else {
#pragma unroll
      for (int kk = 0; kk < 16; ++kk) {
        float4 a0 = *(const float4*)&As[cur][kk][trow];
        float4 a1 = *(const float4*)&As[cur][kk][trow + 4];
        float4 b  = *(const float4*)&Bs[cur][kk][4*jl];
        float av[8] = {a0.x,a0.y,a0.z,a0.w,a1.x,a1.y,a1.z,a1.w};
#pragma unroll
        for (int i = 0; i < 8; ++i) {
          acc[i][0] += av[i] * b.x;
          acc[i][1] += av[i] * b.y;
          acc[i][2] += av[i] * b.z;
          acc[i][3] += av[i] * b.w;
        }
      }
    }
    if (t < 18) {
      const int nxt = cur ^ 1;
      As[nxt][akh+0][ar] = a0r.x; As[nxt][akh+1][ar] = a0r.y; As[nxt][akh+2][ar] = a0r.z; As[nxt][akh+3][ar] = a0r.w;
      As[nxt][akh+4][ar] = a1r.x; As[nxt][akh+5][ar] = a1r.y; As[nxt][akh+6][ar] = a1r.z; As[nxt][akh+7][ar] = a1r.w;
      *(float4*)&Bs[nxt][bk][4*jl] = wr;
    }
    __syncthreads();
  }

  if (j >= 300) return;
  const int r0g = row0 + trow;
  if (leaf) {
    const float bi = b_ioux[j] + b_iouh[j];
    const float bo = b_ioux[300+j] + b_iouh[300+j];
    const float bu = b_ioux[600+j] + b_iouh[600+j];
    float hsum = 0.f;
#pragma unroll
    for (int i = 0; i < 8; ++i) {
      float iv = acc[i][0] + bi;
      float ov = acc[i][1] + bo;
      float uv = acc[i][2] + bu;
      float cc = sigm(iv) * tanhf(uv);
      float hh = sigm(ov) * tanhf(cc);
      const int rel = r0g - 585 + i;
      c_cur[(size_t)rel*300 + j] = cc;
      h_cur[(size_t)rel*300 + j] = hh;
      hsum += hh;
    }
    hsb[(size_t)(73 + ((r0g - 585) >> 3))*300 + j] = hsum;
  } else {
#pragma unroll
    for (int i = 0; i < 8; ++i) {
      const int grow = r0g + i;
      if (grow < NI) {
        xiou[(size_t)grow*900 + j]        = acc[i][0] + b_ioux[j];
        xiou[(size_t)grow*900 + 300 + j]  = acc[i][1] + b_ioux[300+j];
        xiou[(size_t)grow*900 + 600 + j]  = acc[i][2] + b_ioux[600+j];
        fxo[(size_t)grow*300 + j]         = acc[i][3] + b_fx[j];
      }
    }
  }
}

// ---------------- fused iou-GEMM + gates + h-sum ----------------
__global__ __launch_bounds__(256) void ig_kernel(
    int M, int start, int pstart,
    const float* __restrict__ hsb_in, const float* __restrict__ xiou,
    const float* __restrict__ W_iouh, const float* __restrict__ b_iouh,
    const float* __restrict__ fcb,
    float* __restrict__ h_cur, float* __restrict__ c_cur, float* __restrict__ hsb_out)
{
  __shared__ float As[16][132];
  __shared__ float Bs[16][68];
  const int nj = 19;
  const int row0 = (blockIdx.x / nj) * 128;
  const int j0 = (blockIdx.x % nj) * 16;
  const int tid = threadIdx.x;
  float acc[8][3] = {};
  const int trow = (tid >> 4) * 8;
  const int jl   = tid & 15;
  const int j    = j0 + jl;
  const int ar   = tid >> 1;
  const int akh  = (tid & 1) * 8;
  const int bk   = tid >> 4;

  for (int k0 = 0; k0 < 300; k0 += 16) {
    __syncthreads();
    {
      float4 v0 = {0,0,0,0}, v1 = {0,0,0,0};
      const int grow = row0 + ar;
      const int kb = k0 + akh;
      if (grow < M) {
        const float* src = hsb_in + (size_t)(start + grow) * 300;
        if (kb + 3 < 300) v0 = *(const float4*)(src + kb);
        if (kb + 7 < 300) v1 = *(const float4*)(src + kb + 4);
      }
      As[akh+0][ar] = v0.x; As[akh+1][ar] = v0.y; As[akh+2][ar] = v0.z; As[akh+3][ar] = v0.w;
      As[akh+4][ar] = v1.x; As[akh+5][ar] = v1.y; As[akh+6][ar] = v1.z; As[akh+7][ar] = v1.w;
    }
    {
      float w0 = 0.f, w1 = 0.f, w2 = 0.f;
      const int k = k0 + bk;
      if (k < 300 && j < 300) {
        w0 = W_iouh[(size_t)k*900 + j];
        w1 = W_iouh[(size_t)k*900 + 300 + j];
        w2 = W_iouh[(size_t)k*900 + 600 + j];
      }
      Bs[bk][3*jl+0] = w0;
      Bs[bk][3*jl+1] = w1;
      Bs[bk][3*jl+2] = w2;
    }
    __syncthreads();
#pragma unroll
    for (int kk = 0; kk < 16; ++kk) {
      float4 a0 = *(const float4*)&As[kk][trow];
      float4 a1 = *(const float4*)&As[kk][trow + 4];
      float b0 = Bs[kk][3*jl+0];
      float b1 = Bs[kk][3*jl+1];
      float b2 = Bs[kk][3*jl+2];
      float av[8] = {a0.x,a0.y,a0.z,a0.w,a1.x,a1.y,a1.z,a1.w};
#pragma unroll
      for (int i = 0; i < 8; ++i) {
        acc[i][0] += av[i] * b0;
        acc[i][1] += av[i] * b1;
        acc[i][2] += av[i] * b2;
      }
    }
  }
  if (j >= 300) return;
  const int r0 = row0 + trow;
  if (r0 >= M) return;
  float hsum = 0.f;
#pragma unroll
  for (int i = 0; i < 8; ++i) {
    const int node = start + r0 + i;
    float iv = acc[i][0] + xiou[(size_t)node*900 + j]        + b_iouh[j];
    float ov = acc[i][1] + xiou[(size_t)node*900 + 300 + j]  + b_iouh[300+j];
    float uv = acc[i][2] + xiou[(size_t)node*900 + 600 + j]  + b_iouh[600+j];
    float cc = sigm(iv) * tanhf(uv) + fcb[(size_t)node*300 + j];
    float hh = sigm(ov) * tanhf(cc);
    c_cur[(size_t)(r0+i)*300 + j] = cc;
    h_cur[(size_t)(r0+i)*300 + j] = hh;
    hsum += hh;
  }
  hsb_out[(size_t)(pstart + (r0 >> 3))*300 + j] = hsum;
}

// ---------------- W_fh GEMM + fused f-gate + fc reduction ----------------
__global__ __launch_bounds__(256) void fcb_kernel(
    int M, int pstart,
    const float* __restrict__ h_cur, const float* __restrict__ c_cur,
    const float* __restrict__ W_fh, const float* __restrict__ b_fh,
    const float* __restrict__ fxo, float* __restrict__ fcb)
{
  __shared__ float As[16][132];
  __shared__ float Bs[16][68];
  const int row0 = (blockIdx.x / 5) * 128;
  const int col0 = (blockIdx.x % 5) * 64;
  const int tid = threadIdx.x;
  float acc[8][4] = {};
  const int trow = (tid >> 4) * 8;
  const int tcol = (tid & 15) * 4;
  const int ar  = tid >> 1;
  const int akh = (tid & 1) * 8;
  const int bk  = tid >> 4;
  const int bc  = (tid & 15) * 4;
  for (int k0 = 0; k0 < 300; k0 += 16) {
    __syncthreads();
    {
      float4 v0 = {0,0,0,0}, v1 = {0,0,0,0};
      const int grow = row0 + ar;
      const int kb = k0 + akh;
      if (grow < M) {
        const float* src = h_cur + (size_t)grow * 300;
        if (kb + 3 < 300) v0 = *(const float4*)(src + kb);
        if (kb + 7 < 300) v1 = *(const float4*)(src + kb + 4);
      }
      As[akh+0][ar] = v0.x; As[akh+1][ar] = v0.y; As[akh+2][ar] = v0.z; As[akh+3][ar] = v0.w;
      As[akh+4][ar] = v1.x; As[akh+5][ar] = v1.y; As[akh+6][ar] = v1.z; As[akh+7][ar] = v1.w;
    }
    {
      float4 v = {0,0,0,0};
      const int k = k0 + bk;
      const int col = col0 + bc;
      if (k < 300 && col < 300) v = *(const float4*)(W_fh + (size_t)k * 300 + col);
      *(float4*)&Bs[bk][bc] = v;
    }
    __syncthreads();
#pragma unroll
    for (int kk = 0; kk < 16; ++kk) {
      float4 a0 = *(const float4*)&As[kk][trow];
      float4 a1 = *(const float4*)&As[kk][trow + 4];
      float4 b  = *(const float4*)&Bs[kk][tcol];
      float av[8] = {a0.x,a0.y,a0.z,a0.w,a1.x,a1.y,a1.z,a1.w};
      float bv[4] = {b.x,b.y,b.z,b.w};
#pragma unroll
      for (int i = 0; i < 8; ++i)
#pragma unroll
        for (int jj = 0; jj < 4; ++jj) acc[i][jj] += av[i] * bv[jj];
    }
  }
  const int r0 = row0 + trow;
  if (r0 < M) {
    const int p = pstart + (r0 >> 3);
#pragma unroll
    for (int jj = 0; jj < 4; ++jj) {
      const int col = col0 + tcol + jj;
      if (col >= 300) continue;
      const float add = b_fh[col] + fxo[(size_t)p*300 + col];
      float fc = 0.f;
#pragma unroll
      for (int i = 0; i < 8; ++i)
        fc += sigm(acc[i][jj] + add) * c_cur[(size_t)(r0 + i)*300 + col];
      fcb[(size_t)p*300 + col] = fc;
    }
  }
}

// ---------------- root: gates + W_lin head ----------------
__global__ __launch_bounds__(256) void root_kernel(
    const float* __restrict__ xiou,
    const float* __restrict__ W_iouh, const float* __restrict__ b_iouh,
    const float* __restrict__ hsb, const float* __restrict__ fcb,
    const float* __restrict__ W_lin, const float* __restrict__ b_lin,
    float* __restrict__ out)
{
  __shared__ float hs[300];
  __shared__ float siou[900];
  __shared__ float sc[300];
  __shared__ float sh[300];
  const int tid = threadIdx.x;
  for (int j = tid; j < 300; j += 256) hs[j] = hsb[j];
  __syncthreads();
  for (int j = tid; j < 900; j += 256) {
    float acc = xiou[j] + b_iouh[j];
    for (int k = 0; k < 300; ++k) acc += hs[k] * W_iouh[k*900 + j];
    siou[j] = acc;
  }
  __syncthreads();
  for (int j = tid; j < 300; j += 256) {
    float cc = sigm(siou[j]) * tanhf(siou[600 + j]) + fcb[j];
    sc[j] = cc;
    sh[j] = sigm(siou[300 + j]) * tanhf(cc);
  }
  __syncthreads();
  for (int j = tid; j < 42; j += 256) {
    float acc = b_lin[j];
    for (int k = 0; k < 300; ++k) acc += sc[k] * W_lin[k*42 + j];
    out[j] = acc;
  }
  for (int j = tid; j < 300; j += 256) out[42 + j] = sh[j];
}

extern "C" void kernel_launch(void* const* d_in, const int* in_sizes, int n_in,
                              void* d_out, int out_size, void* d_ws, size_t ws_size,
                              hipStream_t stream) {
  const int* tokens   = (const int*)d_in[0];
  const float* embed  = (const float*)d_in[3];
  const float* W_ioux = (const float*)d_in[4];
  const float* b_ioux = (const float*)d_in[5];
  const float* W_iouh = (const float*)d_in[6];
  const float* b_iouh = (const float*)d_in[7];
  const float* W_fx   = (const float*)d_in[8];
  const float* b_fx   = (const float*)d_in[9];
  const float* W_fh   = (const float*)d_in[10];
  const float* b_fh   = (const float*)d_in[11];
  const float* W_lin  = (const float*)d_in[12];
  const float* b_lin  = (const float*)d_in[13];
  float* out = (float*)d_out;

  float* ws    = (float*)d_ws;
  float* xiou  = ws;                                 // NI*900 (internal rows only)
  float* fxo   = xiou  + (size_t)NI * 900;           // NI*300
  float* hsb   = fxo   + (size_t)NI * 300;           // NI*300
  float* fcb   = hsb   + (size_t)NI * 300;           // NI*300
  float* h_cur = fcb   + (size_t)NI * 300;           // 4096*300
  float* c_cur = h_cur + (size_t)4096 * 300;         // 4096*300

  // K0: merged X-GEMM (internal + leaf) 37x19 tiles
  fx_kernel<<<37*19, 256, 0, stream>>>(tokens, embed, W_ioux, W_fx,
      b_ioux, b_fx, b_iouh, xiou, fxo, h_cur, c_cur, hsb);
  // K1: fcb leaf (parents 73..584)
  fcb_kernel<<<32*5, 256, 0, stream>>>(4096, 73, h_cur, c_cur, W_fh, b_fh, fxo, fcb);
  // K2: ig 512 (nodes 73..584 -> parents 9..72)
  ig_kernel<<<4*19, 256, 0, stream>>>(512, 73, 9, hsb, xiou, W_iouh, b_iouh, fcb, h_cur, c_cur, hsb);
  // K3: fcb 512
  fcb_kernel<<<4*5, 256, 0, stream>>>(512, 9, h_cur, c_cur, W_fh, b_fh, fxo, fcb);
  // K4: ig 64 (nodes 9..72 -> parents 1..8)
  ig_kernel<<<19, 256, 0, stream>>>(64, 9, 1, hsb, xiou, W_iouh, b_iouh, fcb, h_cur, c_cur, hsb);
  // K5: fcb 64
  fcb_kernel<<<5, 256, 0, stream>>>(64, 1, h_cur, c_cur, W_fh, b_fh, fxo, fcb);
  // K6: ig 8 (nodes 1..8 -> parent 0)
  ig_kernel<<<19, 256, 0, stream>>>(8, 1, 0, hsb, xiou, W_iouh, b_iouh, fcb, h_cur, c_cur, hsb);
  // K7: fcb 8 (root)
  fcb_kernel<<<5, 256, 0, stream>>>(8, 0, h_cur, c_cur, W_fh, b_fh, fxo, fcb);
  // K8: root
  root_kernel<<<1, 256, 0, stream>>>(xiou, W_iouh, b_iouh, hsb, fcb, W_lin, b_lin, out);
}

// Round 11
// 312.513 us; speedup vs baseline: 3.5261x; 1.2893x over previous
//
#include <hip/hip_runtime.h>

#define NN 4681        // total nodes
#define NI 585         // internal (parent) nodes
#define KP 320         // K padded to multiple of 32

typedef __bf16 bf16x8 __attribute__((ext_vector_type(8)));
typedef float f32x4 __attribute__((ext_vector_type(4)));
typedef unsigned short u16x4 __attribute__((ext_vector_type(4)));

__device__ __forceinline__ float sigm(float x) { return 1.f / (1.f + expf(-x)); }

__device__ __forceinline__ unsigned short f2bf(float x) {
  unsigned u = __float_as_uint(x);
  u += 0x7FFFu + ((u >> 16) & 1u);
  return (unsigned short)(u >> 16);
}

__device__ __forceinline__ bf16x8 mk_frag(const unsigned short* lo, const unsigned short* hi) {
  union { u16x4 p[2]; bf16x8 v; } t;
  t.p[0] = *(const u16x4*)lo;
  t.p[1] = *(const u16x4*)hi;
  return t.v;
}

// ---------------- prep: bf16 copies (K padded to 320 with zeros) ----------------
// blocks: [0,4681) Xb rows; [4681,5881) WT rows; [5881,6181) WfhT rows; [6181,6437) h_bf pad zero
__global__ __launch_bounds__(256) void prep_kernel(
    const int* __restrict__ tokens, const float* __restrict__ embed,
    const float* __restrict__ W_ioux, const float* __restrict__ W_fx,
    const float* __restrict__ W_fh,
    unsigned short* __restrict__ Xb, unsigned short* __restrict__ WT,
    unsigned short* __restrict__ WfhT, unsigned short* __restrict__ h_bf)
{
  const int bid = blockIdx.x, tid = threadIdx.x;
  if (bid < 4681) {
    const int r = bid;
    const size_t srcb = (size_t)tokens[r] * 300;
    for (int k = tid; k < KP; k += 256) {
      float v = (k < 300) ? embed[srcb + k] : 0.f;
      Xb[(size_t)r * KP + k] = f2bf(v);
    }
  } else if (bid < 5881) {
    const int c = bid - 4681;
    for (int k = tid; k < KP; k += 256) {
      float v = 0.f;
      if (k < 300) v = (c < 900) ? W_ioux[(size_t)k * 900 + c] : W_fx[(size_t)k * 300 + (c - 900)];
      WT[(size_t)c * KP + k] = f2bf(v);
    }
  } else if (bid < 6181) {
    const int c = bid - 5881;
    for (int k = tid; k < KP; k += 256) {
      float v = (k < 300) ? W_fh[(size_t)k * 300 + c] : 0.f;
      WfhT[(size_t)c * KP + k] = f2bf(v);
    }
  } else {
    const int r0 = (bid - 6181) * 16;
    for (int idx = tid; idx < 320; idx += 256) {
      const int r = r0 + idx / 20, k = 300 + idx % 20;
      h_bf[(size_t)r * KP + k] = 0;
    }
  }
}

// ---------------- MFMA X-GEMM: internal -> xiou+fxo; leaf -> gates+c/h+hsb ----------------
// Grid 74x19: rt<10 internal rows rt*64; rt>=10 leaf rows 585+(rt-10)*64. 16-col j-strip.
// Per wave: 16 rows x 16 cols x {i,o,u[,fx]} planes; K loop 10 x 32.
__global__ __launch_bounds__(256) void fx_mfma(
    const unsigned short* __restrict__ Xb, const unsigned short* __restrict__ WT,
    const float* __restrict__ b_ioux, const float* __restrict__ b_fx,
    const float* __restrict__ b_iouh,
    float* __restrict__ xiou, float* __restrict__ fxo,
    float* __restrict__ c_cur, unsigned short* __restrict__ h_bf, float* __restrict__ hsb)
{
  __shared__ unsigned short As[64][48];
  __shared__ unsigned short Bs[4][16][48];
  const int tid = threadIdx.x;
  const int rt = blockIdx.x / 19, jt = blockIdx.x % 19;
  const bool leaf = (rt >= 10);
  const int R0 = leaf ? (585 + (rt - 10) * 64) : rt * 64;
  const int j0 = jt * 16;
  const int w = tid >> 6, lane = tid & 63, q = lane >> 4, cl = lane & 15;
  const int srow = tid >> 2, sk = (tid & 3) * 8;
  const int bp = tid >> 6, bcol = (tid >> 2) & 15;

  f32x4 acc[4] = {{0,0,0,0},{0,0,0,0},{0,0,0,0},{0,0,0,0}};
  for (int kt = 0; kt < 10; ++kt) {
    const int k0 = kt * 32;
    __syncthreads();
    *(uint4*)&As[srow][sk] = *(const uint4*)(Xb + (size_t)(R0 + srow) * KP + k0 + sk);
    {
      uint4 wv = {0, 0, 0, 0};
      const int cg = j0 + bcol;
      if (cg < 300 && (bp < 3 || !leaf))
        wv = *(const uint4*)(WT + (size_t)(bp * 300 + cg) * KP + k0 + sk);
      *(uint4*)&Bs[bp][bcol][sk] = wv;
    }
    __syncthreads();
    bf16x8 af = mk_frag(&As[16 * w + cl][4 * q], &As[16 * w + cl][16 + 4 * q]);
#pragma unroll
    for (int p = 0; p < 4; ++p) {
      if (!(p == 3 && leaf)) {
        bf16x8 bf = mk_frag(&Bs[p][cl][4 * q], &Bs[p][cl][16 + 4 * q]);
        acc[p] = __builtin_amdgcn_mfma_f32_16x16x32_bf16(af, bf, acc[p], 0, 0, 0);
      }
    }
  }

  const int jj = j0 + cl;
  if (jj >= 300) return;
  if (leaf) {
    const float bi = b_ioux[jj] + b_iouh[jj];
    const float bo = b_ioux[300 + jj] + b_iouh[300 + jj];
    const float bu = b_ioux[600 + jj] + b_iouh[600 + jj];
    float hsum = 0.f;
#pragma unroll
    for (int r = 0; r < 4; ++r) {
      const int rel = (R0 - 585) + 16 * w + 4 * q + r;
      float iv = acc[0][r] + bi, ov = acc[1][r] + bo, uv = acc[2][r] + bu;
      float cv = sigm(iv) * tanhf(uv);
      float hv = sigm(ov) * tanhf(cv);
      c_cur[(size_t)rel * 300 + jj] = cv;
      h_bf[(size_t)rel * KP + jj] = f2bf(hv);
      hsum += hv;
    }
    float tot = hsum + __shfl_xor(hsum, 16);
    if ((q & 1) == 0) {
      const int p = 73 + ((R0 - 585 + 16 * w) >> 3) + (q >> 1);
      hsb[(size_t)p * 300 + jj] = tot;
    }
  } else {
#pragma unroll
    for (int r = 0; r < 4; ++r) {
      const int grow = R0 + 16 * w + 4 * q + r;
      if (grow < NI) {
        xiou[(size_t)grow * 900 + jj]       = acc[0][r] + b_ioux[jj];
        xiou[(size_t)grow * 900 + 300 + jj] = acc[1][r] + b_ioux[300 + jj];
        xiou[(size_t)grow * 900 + 600 + jj] = acc[2][r] + b_ioux[600 + jj];
        fxo[(size_t)grow * 300 + jj]        = acc[3][r] + b_fx[jj];
      }
    }
  }
}

// ---------------- MFMA W_fh GEMM + fused f-gate + fc reduction (leaf level) ----------------
// Grid 64x19: rows rt*64 of 4096 leaf children, 16-col strip. Parents 73..584.
__global__ __launch_bounds__(256) void fcbleaf_mfma(
    const unsigned short* __restrict__ h_bf, const unsigned short* __restrict__ WfhT,
    const float* __restrict__ c_cur, const float* __restrict__ b_fh,
    const float* __restrict__ fxo, float* __restrict__ fcb)
{
  __shared__ unsigned short As[64][48];
  __shared__ unsigned short Bs[16][48];
  const int tid = threadIdx.x;
  const int rt = blockIdx.x / 19, jt = blockIdx.x % 19;
  const int R0 = rt * 64;
  const int j0 = jt * 16;
  const int w = tid >> 6, lane = tid & 63, q = lane >> 4, cl = lane & 15;
  const int srow = tid >> 2, sk = (tid & 3) * 8;

  f32x4 acc = {0, 0, 0, 0};
  for (int kt = 0; kt < 10; ++kt) {
    const int k0 = kt * 32;
    __syncthreads();
    *(uint4*)&As[srow][sk] = *(const uint4*)(h_bf + (size_t)(R0 + srow) * KP + k0 + sk);
    if (tid < 64) {
      const int col = tid >> 2, ks = (tid & 3) * 8;
      uint4 wv = {0, 0, 0, 0};
      const int cg = j0 + col;
      if (cg < 300) wv = *(const uint4*)(WfhT + (size_t)cg * KP + k0 + ks);
      *(uint4*)&Bs[col][ks] = wv;
    }
    __syncthreads();
    bf16x8 af = mk_frag(&As[16 * w + cl][4 * q], &As[16 * w + cl][16 + 4 * q]);
    bf16x8 bf = mk_frag(&Bs[cl][4 * q], &Bs[cl][16 + 4 * q]);
    acc = __builtin_amdgcn_mfma_f32_16x16x32_bf16(af, bf, acc, 0, 0, 0);
  }

  const int jj = j0 + cl;
  if (jj >= 300) return;
  const int p = 73 + ((R0 + 16 * w) >> 3) + (q >> 1);
  const float add = b_fh[jj] + fxo[(size_t)p * 300 + jj];
  float fc = 0.f;
#pragma unroll
  for (int r = 0; r < 4; ++r) {
    const int rel = R0 + 16 * w + 4 * q + r;
    float f = sigm(acc[r] + add);
    fc += f * c_cur[(size_t)rel * 300 + jj];
  }
  float tot = fc + __shfl_xor(fc, 16);
  if ((q & 1) == 0) fcb[(size_t)p * 300 + jj] = tot;
}

// ---------------- fp32 fused iou-GEMM + gates + h-sum (upper levels) ----------------
__global__ __launch_bounds__(256) void ig_kernel(
    int M, int start, int pstart,
    const float* __restrict__ hsb_in, const float* __restrict__ xiou,
    const float* __restrict__ W_iouh, const float* __restrict__ b_iouh,
    const float* __restrict__ fcb,
    float* __restrict__ h_cur, float* __restrict__ c_cur, float* __restrict__ hsb_out)
{
  __shared__ float As[16][132];
  __shared__ float Bs[16][68];
  const int nj = 19;
  const int row0 = (blockIdx.x / nj) * 128;
  const int j0 = (blockIdx.x % nj) * 16;
  const int tid = threadIdx.x;
  float acc[8][3] = {};
  const int trow = (tid >> 4) * 8;
  const int jl   = tid & 15;
  const int j    = j0 + jl;
  const int ar   = tid >> 1;
  const int akh  = (tid & 1) * 8;
  const int bk   = tid >> 4;

  for (int k0 = 0; k0 < 300; k0 += 16) {
    __syncthreads();
    {
      float4 v0 = {0,0,0,0}, v1 = {0,0,0,0};
      const int grow = row0 + ar;
      const int kb = k0 + akh;
      if (grow < M) {
        const float* src = hsb_in + (size_t)(start + grow) * 300;
        if (kb + 3 < 300) v0 = *(const float4*)(src + kb);
        if (kb + 7 < 300) v1 = *(const float4*)(src + kb + 4);
      }
      As[akh+0][ar] = v0.x; As[akh+1][ar] = v0.y; As[akh+2][ar] = v0.z; As[akh+3][ar] = v0.w;
      As[akh+4][ar] = v1.x; As[akh+5][ar] = v1.y; As[akh+6][ar] = v1.z; As[akh+7][ar] = v1.w;
    }
    {
      float w0 = 0.f, w1 = 0.f, w2 = 0.f;
      const int k = k0 + bk;
      if (k < 300 && j < 300) {
        w0 = W_iouh[(size_t)k*900 + j];
        w1 = W_iouh[(size_t)k*900 + 300 + j];
        w2 = W_iouh[(size_t)k*900 + 600 + j];
      }
      Bs[bk][3*jl+0] = w0;
      Bs[bk][3*jl+1] = w1;
      Bs[bk][3*jl+2] = w2;
    }
    __syncthreads();
#pragma unroll
    for (int kk = 0; kk < 16; ++kk) {
      float4 a0 = *(const float4*)&As[kk][trow];
      float4 a1 = *(const float4*)&As[kk][trow + 4];
      float b0 = Bs[kk][3*jl+0];
      float b1 = Bs[kk][3*jl+1];
      float b2 = Bs[kk][3*jl+2];
      float av[8] = {a0.x,a0.y,a0.z,a0.w,a1.x,a1.y,a1.z,a1.w};
#pragma unroll
      for (int i = 0; i < 8; ++i) {
        acc[i][0] += av[i] * b0;
        acc[i][1] += av[i] * b1;
        acc[i][2] += av[i] * b2;
      }
    }
  }
  if (j >= 300) return;
  const int r0 = row0 + trow;
  if (r0 >= M) return;
  float hsum = 0.f;
#pragma unroll
  for (int i = 0; i < 8; ++i) {
    const int node = start + r0 + i;
    float iv = acc[i][0] + xiou[(size_t)node*900 + j]        + b_iouh[j];
    float ov = acc[i][1] + xiou[(size_t)node*900 + 300 + j]  + b_iouh[300+j];
    float uv = acc[i][2] + xiou[(size_t)node*900 + 600 + j]  + b_iouh[600+j];
    float cc = sigm(iv) * tanhf(uv) + fcb[(size_t)node*300 + j];
    float hh = sigm(ov) * tanhf(cc);
    c_cur[(size_t)(r0+i)*300 + j] = cc;
    h_cur[(size_t)(r0+i)*300 + j] = hh;
    hsum += hh;
  }
  hsb_out[(size_t)(pstart + (r0 >> 3))*300 + j] = hsum;
}

// ---------------- fp32 W_fh GEMM + fused f-gate + fc reduction (upper levels) ----------------
__global__ __launch_bounds__(256) void fcb_kernel(
    int M, int pstart,
    const float* __restrict__ h_cur, const float* __restrict__ c_cur,
    const float* __restrict__ W_fh, const float* __restrict__ b_fh,
    const float* __restrict__ fxo, float* __restrict__ fcb)
{
  __shared__ float As[16][132];
  __shared__ float Bs[16][68];
  const int row0 = (blockIdx.x / 5) * 128;
  const int col0 = (blockIdx.x % 5) * 64;
  const int tid = threadIdx.x;
  float acc[8][4] = {};
  const int trow = (tid >> 4) * 8;
  const int tcol = (tid & 15) * 4;
  const int ar  = tid >> 1;
  const int akh = (tid & 1) * 8;
  const int bk  = tid >> 4;
  const int bc  = (tid & 15) * 4;
  for (int k0 = 0; k0 < 300; k0 += 16) {
    __syncthreads();
    {
      float4 v0 = {0,0,0,0}, v1 = {0,0,0,0};
      const int grow = row0 + ar;
      const int kb = k0 + akh;
      if (grow < M) {
        const float* src = h_cur + (size_t)grow * 300;
        if (kb + 3 < 300) v0 = *(const float4*)(src + kb);
        if (kb + 7 < 300) v1 = *(const float4*)(src + kb + 4);
      }
      As[akh+0][ar] = v0.x; As[akh+1][ar] = v0.y; As[akh+2][ar] = v0.z; As[akh+3][ar] = v0.w;
      As[akh+4][ar] = v1.x; As[akh+5][ar] = v1.y; As[akh+6][ar] = v1.z; As[akh+7][ar] = v1.w;
    }
    {
      float4 v = {0,0,0,0};
      const int k = k0 + bk;
      const int col = col0 + bc;
      if (k < 300 && col < 300) v = *(const float4*)(W_fh + (size_t)k * 300 + col);
      *(float4*)&Bs[bk][bc] = v;
    }
    __syncthreads();
#pragma unroll
    for (int kk = 0; kk < 16; ++kk) {
      float4 a0 = *(const float4*)&As[kk][trow];
      float4 a1 = *(const float4*)&As[kk][trow + 4];
      float4 b  = *(const float4*)&Bs[kk][tcol];
      float av[8] = {a0.x,a0.y,a0.z,a0.w,a1.x,a1.y,a1.z,a1.w};
      float bv[4] = {b.x,b.y,b.z,b.w};
#pragma unroll
      for (int i = 0; i < 8; ++i)
#pragma unroll
        for (int jj = 0; jj < 4; ++jj) acc[i][jj] += av[i] * bv[jj];
    }
  }
  const int r0 = row0 + trow;
  if (r0 < M) {
    const int p = pstart + (r0 >> 3);
#pragma unroll
    for (int jj = 0; jj < 4; ++jj) {
      const int col = col0 + tcol + jj;
      if (col >= 300) continue;
      const float add = b_fh[col] + fxo[(size_t)p*300 + col];
      float fc = 0.f;
#pragma unroll
      for (int i = 0; i < 8; ++i)
        fc += sigm(acc[i][jj] + add) * c_cur[(size_t)(r0 + i)*300 + col];
      fcb[(size_t)p*300 + col] = fc;
    }
  }
}

// ---------------- root: gates + W_lin head ----------------
__global__ __launch_bounds__(256) void root_kernel(
    const float* __restrict__ xiou,
    const float* __restrict__ W_iouh, const float* __restrict__ b_iouh,
    const float* __restrict__ hsb, const float* __restrict__ fcb,
    const float* __restrict__ W_lin, const float* __restrict__ b_lin,
    float* __restrict__ out)
{
  __shared__ float hs[300];
  __shared__ float siou[900];
  __shared__ float sc[300];
  __shared__ float sh[300];
  const int tid = threadIdx.x;
  for (int j = tid; j < 300; j += 256) hs[j] = hsb[j];
  __syncthreads();
  for (int j = tid; j < 900; j += 256) {
    float acc = xiou[j] + b_iouh[j];
    for (int k = 0; k < 300; ++k) acc += hs[k] * W_iouh[k*900 + j];
    siou[j] = acc;
  }
  __syncthreads();
  for (int j = tid; j < 300; j += 256) {
    float cc = sigm(siou[j]) * tanhf(siou[600 + j]) + fcb[j];
    sc[j] = cc;
    sh[j] = sigm(siou[300 + j]) * tanhf(cc);
  }
  __syncthreads();
  for (int j = tid; j < 42; j += 256) {
    float acc = b_lin[j];
    for (int k = 0; k < 300; ++k) acc += sc[k] * W_lin[k*42 + j];
    out[j] = acc;
  }
  for (int j = tid; j < 300; j += 256) out[42 + j] = sh[j];
}

extern "C" void kernel_launch(void* const* d_in, const int* in_sizes, int n_in,
                              void* d_out, int out_size, void* d_ws, size_t ws_size,
                              hipStream_t stream) {
  const int* tokens   = (const int*)d_in[0];
  const float* embed  = (const float*)d_in[3];
  const float* W_ioux = (const float*)d_in[4];
  const float* b_ioux = (const float*)d_in[5];
  const float* W_iouh = (const float*)d_in[6];
  const float* b_iouh = (const float*)d_in[7];
  const float* W_fx   = (const float*)d_in[8];
  const float* b_fx   = (const float*)d_in[9];
  const float* W_fh   = (const float*)d_in[10];
  const float* b_fh   = (const float*)d_in[11];
  const float* W_lin  = (const float*)d_in[12];
  const float* b_lin  = (const float*)d_in[13];
  float* out = (float*)d_out;

  float* ws    = (float*)d_ws;
  float* xiou  = ws;                                 // 585*900
  float* fxo   = xiou  + (size_t)NI * 900;           // 585*300
  float* hsb   = fxo   + (size_t)NI * 300;           // 585*300
  float* fcb   = hsb   + (size_t)NI * 300;           // 585*300
  float* c_cur = fcb   + (size_t)NI * 300;           // 4096*300
  float* h_cur = c_cur + (size_t)4096 * 300;         // 512*300 (upper levels)
  unsigned short* Xb   = (unsigned short*)(h_cur + (size_t)512 * 300);
  unsigned short* h_bf = Xb   + (size_t)NN * KP;     // 4096*320
  unsigned short* WT   = h_bf + (size_t)4096 * KP;   // 1200*320
  unsigned short* WfhT = WT   + (size_t)1200 * KP;   // 300*320

  // P: bf16 copies + pads
  prep_kernel<<<6437, 256, 0, stream>>>(tokens, embed, W_ioux, W_fx, W_fh,
      Xb, WT, WfhT, h_bf);
  // K0: MFMA X-GEMM (internal xiou/fxo + leaf gates/c/h/hsb)
  fx_mfma<<<74 * 19, 256, 0, stream>>>(Xb, WT, b_ioux, b_fx, b_iouh,
      xiou, fxo, c_cur, h_bf, hsb);
  // K1: MFMA fcb leaf (parents 73..584)
  fcbleaf_mfma<<<64 * 19, 256, 0, stream>>>(h_bf, WfhT, c_cur, b_fh, fxo, fcb);
  // K2: ig 512 (nodes 73..584 -> parents 9..72)
  ig_kernel<<<4*19, 256, 0, stream>>>(512, 73, 9, hsb, xiou, W_iouh, b_iouh, fcb, h_cur, c_cur, hsb);
  // K3: fcb 512
  fcb_kernel<<<4*5, 256, 0, stream>>>(512, 9, h_cur, c_cur, W_fh, b_fh, fxo, fcb);
  // K4: ig 64 (nodes 9..72 -> parents 1..8)
  ig_kernel<<<19, 256, 0, stream>>>(64, 9, 1, hsb, xiou, W_iouh, b_iouh, fcb, h_cur, c_cur, hsb);
  // K5: fcb 64
  fcb_kernel<<<5, 256, 0, stream>>>(64, 1, h_cur, c_cur, W_fh, b_fh, fxo, fcb);
  // K6: ig 8 (nodes 1..8 -> parent 0)
  ig_kernel<<<19, 256, 0, stream>>>(8, 1, 0, hsb, xiou, W_iouh, b_iouh, fcb, h_cur, c_cur, hsb);
  // K7: fcb 8 (root)
  fcb_kernel<<<5, 256, 0, stream>>>(8, 0, h_cur, c_cur, W_fh, b_fh, fxo, fcb);
  // K8: root
  root_kernel<<<1, 256, 0, stream>>>(xiou, W_iouh, b_iouh, hsb, fcb, W_lin, b_lin, out);
}

// Round 12
// 260.078 us; speedup vs baseline: 4.2370x; 1.2016x over previous
//
#include <hip/hip_runtime.h>

#define NN 4681        // total nodes
#define NI 585         // internal (parent) nodes
#define KP 320         // K padded to multiple of 32

typedef __bf16 bf16x8 __attribute__((ext_vector_type(8)));
typedef float f32x4 __attribute__((ext_vector_type(4)));
typedef unsigned short u16x4 __attribute__((ext_vector_type(4)));

__device__ __forceinline__ float sigm(float x) { return 1.f / (1.f + expf(-x)); }

__device__ __forceinline__ unsigned short f2bf(float x) {
  unsigned u = __float_as_uint(x);
  u += 0x7FFFu + ((u >> 16) & 1u);
  return (unsigned short)(u >> 16);
}

__device__ __forceinline__ bf16x8 mk_frag(const unsigned short* lo, const unsigned short* hi) {
  union { u16x4 p[2]; bf16x8 v; } t;
  t.p[0] = *(const u16x4*)lo;
  t.p[1] = *(const u16x4*)hi;
  return t.v;
}

// ---------------- prep: bf16 copies (K padded to 320 with zeros) ----------------
__global__ __launch_bounds__(256) void prep_kernel(
    const int* __restrict__ tokens, const float* __restrict__ embed,
    const float* __restrict__ W_ioux, const float* __restrict__ W_fx,
    const float* __restrict__ W_fh,
    unsigned short* __restrict__ Xb, unsigned short* __restrict__ WT,
    unsigned short* __restrict__ WfhT, unsigned short* __restrict__ h_bf)
{
  const int bid = blockIdx.x, tid = threadIdx.x;
  if (bid < 4681) {
    const int r = bid;
    const size_t srcb = (size_t)tokens[r] * 300;
    for (int k = tid; k < KP; k += 256) {
      float v = (k < 300) ? embed[srcb + k] : 0.f;
      Xb[(size_t)r * KP + k] = f2bf(v);
    }
  } else if (bid < 5881) {
    const int c = bid - 4681;
    for (int k = tid; k < KP; k += 256) {
      float v = 0.f;
      if (k < 300) v = (c < 900) ? W_ioux[(size_t)k * 900 + c] : W_fx[(size_t)k * 300 + (c - 900)];
      WT[(size_t)c * KP + k] = f2bf(v);
    }
  } else if (bid < 6181) {
    const int c = bid - 5881;
    for (int k = tid; k < KP; k += 256) {
      float v = (k < 300) ? W_fh[(size_t)k * 300 + c] : 0.f;
      WfhT[(size_t)c * KP + k] = f2bf(v);
    }
  } else {
    const int r0 = (bid - 6181) * 16;
    for (int idx = tid; idx < 320; idx += 256) {
      const int r = r0 + idx / 20, k = 300 + idx % 20;
      h_bf[(size_t)r * KP + k] = 0;
    }
  }
}

// ---------------- MFMA X-GEMM: internal -> xiou+fxo; leaf -> gates+c/h+hsb ----------------
__global__ __launch_bounds__(256) void fx_mfma(
    const unsigned short* __restrict__ Xb, const unsigned short* __restrict__ WT,
    const float* __restrict__ b_ioux, const float* __restrict__ b_fx,
    const float* __restrict__ b_iouh,
    float* __restrict__ xiou, float* __restrict__ fxo,
    float* __restrict__ c_cur, unsigned short* __restrict__ h_bf, float* __restrict__ hsb)
{
  __shared__ unsigned short As[64][48];
  __shared__ unsigned short Bs[4][16][48];
  const int tid = threadIdx.x;
  const int rt = blockIdx.x / 19, jt = blockIdx.x % 19;
  const bool leaf = (rt >= 10);
  const int R0 = leaf ? (585 + (rt - 10) * 64) : rt * 64;
  const int j0 = jt * 16;
  const int w = tid >> 6, lane = tid & 63, q = lane >> 4, cl = lane & 15;
  const int srow = tid >> 2, sk = (tid & 3) * 8;
  const int bp = tid >> 6, bcol = (tid >> 2) & 15;

  f32x4 acc[4] = {{0,0,0,0},{0,0,0,0},{0,0,0,0},{0,0,0,0}};
  for (int kt = 0; kt < 10; ++kt) {
    const int k0 = kt * 32;
    __syncthreads();
    *(uint4*)&As[srow][sk] = *(const uint4*)(Xb + (size_t)(R0 + srow) * KP + k0 + sk);
    {
      uint4 wv = {0, 0, 0, 0};
      const int cg = j0 + bcol;
      if (cg < 300 && (bp < 3 || !leaf))
        wv = *(const uint4*)(WT + (size_t)(bp * 300 + cg) * KP + k0 + sk);
      *(uint4*)&Bs[bp][bcol][sk] = wv;
    }
    __syncthreads();
    bf16x8 af = mk_frag(&As[16 * w + cl][4 * q], &As[16 * w + cl][16 + 4 * q]);
#pragma unroll
    for (int p = 0; p < 4; ++p) {
      if (!(p == 3 && leaf)) {
        bf16x8 bf = mk_frag(&Bs[p][cl][4 * q], &Bs[p][cl][16 + 4 * q]);
        acc[p] = __builtin_amdgcn_mfma_f32_16x16x32_bf16(af, bf, acc[p], 0, 0, 0);
      }
    }
  }

  const int jj = j0 + cl;
  if (jj >= 300) return;
  if (leaf) {
    const float bi = b_ioux[jj] + b_iouh[jj];
    const float bo = b_ioux[300 + jj] + b_iouh[300 + jj];
    const float bu = b_ioux[600 + jj] + b_iouh[600 + jj];
    float hsum = 0.f;
#pragma unroll
    for (int r = 0; r < 4; ++r) {
      const int rel = (R0 - 585) + 16 * w + 4 * q + r;
      float iv = acc[0][r] + bi, ov = acc[1][r] + bo, uv = acc[2][r] + bu;
      float cv = sigm(iv) * tanhf(uv);
      float hv = sigm(ov) * tanhf(cv);
      c_cur[(size_t)rel * 300 + jj] = cv;
      h_bf[(size_t)rel * KP + jj] = f2bf(hv);
      hsum += hv;
    }
    float tot = hsum + __shfl_xor(hsum, 16);
    if ((q & 1) == 0) {
      const int p = 73 + ((R0 - 585 + 16 * w) >> 3) + (q >> 1);
      hsb[(size_t)p * 300 + jj] = tot;
    }
  } else {
#pragma unroll
    for (int r = 0; r < 4; ++r) {
      const int grow = R0 + 16 * w + 4 * q + r;
      if (grow < NI) {
        xiou[(size_t)grow * 900 + jj]       = acc[0][r] + b_ioux[jj];
        xiou[(size_t)grow * 900 + 300 + jj] = acc[1][r] + b_ioux[300 + jj];
        xiou[(size_t)grow * 900 + 600 + jj] = acc[2][r] + b_ioux[600 + jj];
        fxo[(size_t)grow * 300 + jj]        = acc[3][r] + b_fx[jj];
      }
    }
  }
}

// ---------------- MFMA W_fh GEMM + fused f-gate + fc reduction (leaf level) ----------------
__global__ __launch_bounds__(256) void fcbleaf_mfma(
    const unsigned short* __restrict__ h_bf, const unsigned short* __restrict__ WfhT,
    const float* __restrict__ c_cur, const float* __restrict__ b_fh,
    const float* __restrict__ fxo, float* __restrict__ fcb)
{
  __shared__ unsigned short As[64][48];
  __shared__ unsigned short Bs[16][48];
  const int tid = threadIdx.x;
  const int rt = blockIdx.x / 19, jt = blockIdx.x % 19;
  const int R0 = rt * 64;
  const int j0 = jt * 16;
  const int w = tid >> 6, lane = tid & 63, q = lane >> 4, cl = lane & 15;
  const int srow = tid >> 2, sk = (tid & 3) * 8;

  f32x4 acc = {0, 0, 0, 0};
  for (int kt = 0; kt < 10; ++kt) {
    const int k0 = kt * 32;
    __syncthreads();
    *(uint4*)&As[srow][sk] = *(const uint4*)(h_bf + (size_t)(R0 + srow) * KP + k0 + sk);
    if (tid < 64) {
      const int col = tid >> 2, ks = (tid & 3) * 8;
      uint4 wv = {0, 0, 0, 0};
      const int cg = j0 + col;
      if (cg < 300) wv = *(const uint4*)(WfhT + (size_t)cg * KP + k0 + ks);
      *(uint4*)&Bs[col][ks] = wv;
    }
    __syncthreads();
    bf16x8 af = mk_frag(&As[16 * w + cl][4 * q], &As[16 * w + cl][16 + 4 * q]);
    bf16x8 bf = mk_frag(&Bs[cl][4 * q], &Bs[cl][16 + 4 * q]);
    acc = __builtin_amdgcn_mfma_f32_16x16x32_bf16(af, bf, acc, 0, 0, 0);
  }

  const int jj = j0 + cl;
  if (jj >= 300) return;
  const int p = 73 + ((R0 + 16 * w) >> 3) + (q >> 1);
  const float add = b_fh[jj] + fxo[(size_t)p * 300 + jj];
  float fc = 0.f;
#pragma unroll
  for (int r = 0; r < 4; ++r) {
    const int rel = R0 + 16 * w + 4 * q + r;
    float f = sigm(acc[r] + add);
    fc += f * c_cur[(size_t)rel * 300 + jj];
  }
  float tot = fc + __shfl_xor(fc, 16);
  if ((q & 1) == 0) fcb[(size_t)p * 300 + jj] = tot;
}

// ---------------- fused level kernel: one block = one parent group (8 sibling nodes) ----
// Computes iou-GEMV + gates + h-sum + fcb reduction for its parent, entirely in-block.
// do_root: additionally computes the root node (iou, gates, W_lin head) from LDS-held sums.
__global__ __launch_bounds__(320) void lvl_kernel(
    int start, int do_root,
    const float* __restrict__ xiou, const float* __restrict__ fxo,
    const float* __restrict__ W_iouh, const float* __restrict__ b_iouh,
    const float* __restrict__ W_fh, const float* __restrict__ b_fh,
    const float* __restrict__ hsb_in, const float* __restrict__ fcb_in,
    float* __restrict__ hsb_out, float* __restrict__ fcb_out,
    const float* __restrict__ W_lin, const float* __restrict__ b_lin,
    float* __restrict__ out)
{
  __shared__ float hs[8][300];
  __shared__ float hc[8][304];
  __shared__ float cc[8][304];
  __shared__ float fcr[304];
  const int bp = blockIdx.x;
  const int n0 = start + 8 * bp;
  const int p  = (n0 - 1) >> 3;
  const int tid = threadIdx.x;

  for (int idx = tid; idx < 8 * 300; idx += 320) {
    int n = idx / 300, j = idx - n * 300;
    hs[n][j] = hsb_in[(size_t)(n0 + n) * 300 + j];
  }
  __syncthreads();

  // iou GEMV (8 nodes share each W column) + gates + h-sum
  if (tid < 300) {
    const int j = tid;
    float ai[8] = {}, ao[8] = {}, au[8] = {};
#pragma unroll 4
    for (int k = 0; k < 300; ++k) {
      const float wi = W_iouh[(size_t)k * 900 + j];
      const float wo = W_iouh[(size_t)k * 900 + 300 + j];
      const float wu = W_iouh[(size_t)k * 900 + 600 + j];
#pragma unroll
      for (int n = 0; n < 8; ++n) {
        const float h = hs[n][k];
        ai[n] += h * wi; ao[n] += h * wo; au[n] += h * wu;
      }
    }
    float hsum = 0.f;
#pragma unroll
    for (int n = 0; n < 8; ++n) {
      const int node = n0 + n;
      float iv = ai[n] + xiou[(size_t)node * 900 + j]       + b_iouh[j];
      float ov = ao[n] + xiou[(size_t)node * 900 + 300 + j] + b_iouh[300 + j];
      float uv = au[n] + xiou[(size_t)node * 900 + 600 + j] + b_iouh[600 + j];
      float cv = sigm(iv) * tanhf(uv) + fcb_in[(size_t)node * 300 + j];
      float hv = sigm(ov) * tanhf(cv);
      cc[n][j] = cv; hc[n][j] = hv;
      hsum += hv;
    }
    hsb_out[(size_t)p * 300 + j] = hsum;
    if (do_root) hs[0][j] = hsum;          // keep root h_sum in LDS (hs row 0 reused)
  }
  __syncthreads();

  // fcb reduction: f = sigm(h @ W_fh + b_fh + fx[p]); fcb[p] = sum f*c
  if (tid < 300) {
    const int j = tid;
    float a[8] = {};
#pragma unroll 4
    for (int k = 0; k < 300; ++k) {
      const float w = W_fh[(size_t)k * 300 + j];
#pragma unroll
      for (int n = 0; n < 8; ++n) a[n] += hc[n][k] * w;
    }
    const float add = b_fh[j] + fxo[(size_t)p * 300 + j];
    float fc = 0.f;
#pragma unroll
    for (int n = 0; n < 8; ++n) fc += sigm(a[n] + add) * cc[n][j];
    fcb_out[(size_t)p * 300 + j] = fc;
    if (do_root) fcr[j] = fc;
  }
  if (!do_root) return;
  __syncthreads();

  // ---- root (node 0): iou + gates + W_lin head ----
  float* siou = &hs[1][0];   // 900 floats (hs rows 1..3 dead)
  for (int j = tid; j < 900; j += 320) {
    float acc = xiou[j] + b_iouh[j];
    for (int k = 0; k < 300; ++k) acc += hs[0][k] * W_iouh[(size_t)k * 900 + j];
    siou[j] = acc;
  }
  __syncthreads();
  if (tid < 300) {
    const int j = tid;
    float cv = sigm(siou[j]) * tanhf(siou[600 + j]) + fcr[j];
    float hv = sigm(siou[300 + j]) * tanhf(cv);
    cc[0][j] = cv;
    out[42 + j] = hv;
  }
  __syncthreads();
  if (tid < 42) {
    const int j = tid;
    float acc = b_lin[j];
    for (int k = 0; k < 300; ++k) acc += cc[0][k] * W_lin[(size_t)k * 42 + j];
    out[j] = acc;
  }
}

extern "C" void kernel_launch(void* const* d_in, const int* in_sizes, int n_in,
                              void* d_out, int out_size, void* d_ws, size_t ws_size,
                              hipStream_t stream) {
  const int* tokens   = (const int*)d_in[0];
  const float* embed  = (const float*)d_in[3];
  const float* W_ioux = (const float*)d_in[4];
  const float* b_ioux = (const float*)d_in[5];
  const float* W_iouh = (const float*)d_in[6];
  const float* b_iouh = (const float*)d_in[7];
  const float* W_fx   = (const float*)d_in[8];
  const float* b_fx   = (const float*)d_in[9];
  const float* W_fh   = (const float*)d_in[10];
  const float* b_fh   = (const float*)d_in[11];
  const float* W_lin  = (const float*)d_in[12];
  const float* b_lin  = (const float*)d_in[13];
  float* out = (float*)d_out;

  float* ws    = (float*)d_ws;
  float* xiou  = ws;                                 // 585*900
  float* fxo   = xiou  + (size_t)NI * 900;           // 585*300
  float* hsb   = fxo   + (size_t)NI * 300;           // 585*300
  float* fcb   = hsb   + (size_t)NI * 300;           // 585*300
  float* c_cur = fcb   + (size_t)NI * 300;           // 4096*300
  unsigned short* Xb   = (unsigned short*)(c_cur + (size_t)4096 * 300);
  unsigned short* h_bf = Xb   + (size_t)NN * KP;     // 4096*320
  unsigned short* WT   = h_bf + (size_t)4096 * KP;   // 1200*320
  unsigned short* WfhT = WT   + (size_t)1200 * KP;   // 300*320

  // P: bf16 copies + pads
  prep_kernel<<<6437, 256, 0, stream>>>(tokens, embed, W_ioux, W_fx, W_fh,
      Xb, WT, WfhT, h_bf);
  // K0: MFMA X-GEMM (internal xiou/fxo + leaf gates/c/h/hsb)
  fx_mfma<<<74 * 19, 256, 0, stream>>>(Xb, WT, b_ioux, b_fx, b_iouh,
      xiou, fxo, c_cur, h_bf, hsb);
  // K1: MFMA fcb leaf (parents 73..584)
  fcbleaf_mfma<<<64 * 19, 256, 0, stream>>>(h_bf, WfhT, c_cur, b_fh, fxo, fcb);
  // K2: level-512 (nodes 73..584 -> parents 9..72), fused ig+fcb, 64 blocks
  lvl_kernel<<<64, 320, 0, stream>>>(73, 0, xiou, fxo, W_iouh, b_iouh, W_fh, b_fh,
      hsb, fcb, hsb, fcb, W_lin, b_lin, out);
  // K3: level-64 (nodes 9..72 -> parents 1..8), 8 blocks
  lvl_kernel<<<8, 320, 0, stream>>>(9, 0, xiou, fxo, W_iouh, b_iouh, W_fh, b_fh,
      hsb, fcb, hsb, fcb, W_lin, b_lin, out);
  // K4: level-8 (nodes 1..8 -> root) + root head, 1 block
  lvl_kernel<<<1, 320, 0, stream>>>(1, 1, xiou, fxo, W_iouh, b_iouh, W_fh, b_fh,
      hsb, fcb, hsb, fcb, W_lin, b_lin, out);
}

// Round 13
// 155.616 us; speedup vs baseline: 7.0812x; 1.6713x over previous
//
#include <hip/hip_runtime.h>

#define NN 4681        // total nodes
#define NI 585         // internal (parent) nodes
#define KP 320         // K padded to multiple of 32

typedef __bf16 bf16x8 __attribute__((ext_vector_type(8)));
typedef float f32x4 __attribute__((ext_vector_type(4)));
typedef unsigned short u16x4 __attribute__((ext_vector_type(4)));

__device__ __forceinline__ float sigm(float x) { return 1.f / (1.f + expf(-x)); }

__device__ __forceinline__ unsigned short f2bf(float x) {
  unsigned u = __float_as_uint(x);
  u += 0x7FFFu + ((u >> 16) & 1u);
  return (unsigned short)(u >> 16);
}

__device__ __forceinline__ bf16x8 mk_frag(const unsigned short* lo, const unsigned short* hi) {
  union { u16x4 p[2]; bf16x8 v; } t;
  t.p[0] = *(const u16x4*)lo;
  t.p[1] = *(const u16x4*)hi;
  return t.v;
}

// ---------------- prep: bf16 copies (K padded to 320 with zeros) ----------------
__global__ __launch_bounds__(256) void prep_kernel(
    const int* __restrict__ tokens, const float* __restrict__ embed,
    const float* __restrict__ W_ioux, const float* __restrict__ W_fx,
    const float* __restrict__ W_fh, const float* __restrict__ W_iouh,
    unsigned short* __restrict__ Xb, unsigned short* __restrict__ WT,
    unsigned short* __restrict__ WfhT, unsigned short* __restrict__ WiouhT,
    unsigned short* __restrict__ h_bf, unsigned short* __restrict__ hsb_bf)
{
  const int bid = blockIdx.x, tid = threadIdx.x;
  if (bid < 4681) {
    const int r = bid;
    const size_t srcb = (size_t)tokens[r] * 300;
    for (int k = tid; k < KP; k += 256) {
      float v = (k < 300) ? embed[srcb + k] : 0.f;
      Xb[(size_t)r * KP + k] = f2bf(v);
    }
  } else if (bid < 5881) {
    const int c = bid - 4681;
    for (int k = tid; k < KP; k += 256) {
      float v = 0.f;
      if (k < 300) v = (c < 900) ? W_ioux[(size_t)k * 900 + c] : W_fx[(size_t)k * 300 + (c - 900)];
      WT[(size_t)c * KP + k] = f2bf(v);
    }
  } else if (bid < 6181) {
    const int c = bid - 5881;
    for (int k = tid; k < KP; k += 256) {
      float v = (k < 300) ? W_fh[(size_t)k * 300 + c] : 0.f;
      WfhT[(size_t)c * KP + k] = f2bf(v);
    }
  } else if (bid < 7081) {
    const int c = bid - 6181;
    for (int k = tid; k < KP; k += 256) {
      float v = (k < 300) ? W_iouh[(size_t)k * 900 + c] : 0.f;
      WiouhT[(size_t)c * KP + k] = f2bf(v);
    }
  } else if (bid < 7337) {
    const int r0 = (bid - 7081) * 16;
    for (int idx = tid; idx < 320; idx += 256) {
      const int r = r0 + idx / 20, k = 300 + idx % 20;
      h_bf[(size_t)r * KP + k] = 0;
    }
  } else {
    const int r0 = (bid - 7337) * 16;
    for (int idx = tid; idx < 320; idx += 256) {
      const int r = r0 + idx / 20, k = 300 + idx % 20;
      if (r < NI) hsb_bf[(size_t)r * KP + k] = 0;
    }
  }
}

// ---------------- MFMA X-GEMM: internal -> xiou+fxo; leaf -> gates+c/h+hsb ----------------
__global__ __launch_bounds__(256) void fx_mfma(
    const unsigned short* __restrict__ Xb, const unsigned short* __restrict__ WT,
    const float* __restrict__ b_ioux, const float* __restrict__ b_fx,
    const float* __restrict__ b_iouh,
    float* __restrict__ xiou, float* __restrict__ fxo,
    float* __restrict__ c_cur, unsigned short* __restrict__ h_bf,
    float* __restrict__ hsb, unsigned short* __restrict__ hsb_bf)
{
  __shared__ unsigned short As[64][48];
  __shared__ unsigned short Bs[4][16][48];
  const int tid = threadIdx.x;
  const int rt = blockIdx.x / 19, jt = blockIdx.x % 19;
  const bool leaf = (rt >= 10);
  const int R0 = leaf ? (585 + (rt - 10) * 64) : rt * 64;
  const int j0 = jt * 16;
  const int w = tid >> 6, lane = tid & 63, q = lane >> 4, cl = lane & 15;
  const int srow = tid >> 2, sk = (tid & 3) * 8;
  const int bp = tid >> 6, bcol = (tid >> 2) & 15;

  f32x4 acc[4] = {{0,0,0,0},{0,0,0,0},{0,0,0,0},{0,0,0,0}};
  for (int kt = 0; kt < 10; ++kt) {
    const int k0 = kt * 32;
    __syncthreads();
    *(uint4*)&As[srow][sk] = *(const uint4*)(Xb + (size_t)(R0 + srow) * KP + k0 + sk);
    {
      uint4 wv = {0, 0, 0, 0};
      const int cg = j0 + bcol;
      if (cg < 300 && (bp < 3 || !leaf))
        wv = *(const uint4*)(WT + (size_t)(bp * 300 + cg) * KP + k0 + sk);
      *(uint4*)&Bs[bp][bcol][sk] = wv;
    }
    __syncthreads();
    bf16x8 af = mk_frag(&As[16 * w + cl][4 * q], &As[16 * w + cl][16 + 4 * q]);
#pragma unroll
    for (int p = 0; p < 4; ++p) {
      if (!(p == 3 && leaf)) {
        bf16x8 bf = mk_frag(&Bs[p][cl][4 * q], &Bs[p][cl][16 + 4 * q]);
        acc[p] = __builtin_amdgcn_mfma_f32_16x16x32_bf16(af, bf, acc[p], 0, 0, 0);
      }
    }
  }

  const int jj = j0 + cl;
  if (jj >= 300) return;
  if (leaf) {
    const float bi = b_ioux[jj] + b_iouh[jj];
    const float bo = b_ioux[300 + jj] + b_iouh[300 + jj];
    const float bu = b_ioux[600 + jj] + b_iouh[600 + jj];
    float hsum = 0.f;
#pragma unroll
    for (int r = 0; r < 4; ++r) {
      const int rel = (R0 - 585) + 16 * w + 4 * q + r;
      float iv = acc[0][r] + bi, ov = acc[1][r] + bo, uv = acc[2][r] + bu;
      float cv = sigm(iv) * tanhf(uv);
      float hv = sigm(ov) * tanhf(cv);
      c_cur[(size_t)rel * 300 + jj] = cv;
      h_bf[(size_t)rel * KP + jj] = f2bf(hv);
      hsum += hv;
    }
    float tot = hsum + __shfl_xor(hsum, 16);
    if ((q & 1) == 0) {
      const int p = 73 + ((R0 - 585 + 16 * w) >> 3) + (q >> 1);
      hsb[(size_t)p * 300 + jj] = tot;
      hsb_bf[(size_t)p * KP + jj] = f2bf(tot);
    }
  } else {
#pragma unroll
    for (int r = 0; r < 4; ++r) {
      const int grow = R0 + 16 * w + 4 * q + r;
      if (grow < NI) {
        xiou[(size_t)grow * 900 + jj]       = acc[0][r] + b_ioux[jj];
        xiou[(size_t)grow * 900 + 300 + jj] = acc[1][r] + b_ioux[300 + jj];
        xiou[(size_t)grow * 900 + 600 + jj] = acc[2][r] + b_ioux[600 + jj];
        fxo[(size_t)grow * 300 + jj]        = acc[3][r] + b_fx[jj];
      }
    }
  }
}

// ---------------- MFMA iou-GEMM + gates + h-sum for internal levels ----------------
// A = hsb_bf rows [start, start+M); writes c_cur/h_bf rows [0,M), hsb(+bf) parents.
__global__ __launch_bounds__(256) void ig_mfma(
    int M, int start, int pstart,
    const unsigned short* __restrict__ hsb_bf_in, const unsigned short* __restrict__ WiouhT,
    const float* __restrict__ xiou, const float* __restrict__ b_iouh,
    const float* __restrict__ fcb_in,
    float* __restrict__ c_cur, unsigned short* __restrict__ h_bf,
    float* __restrict__ hsb, unsigned short* __restrict__ hsb_bf_out)
{
  __shared__ unsigned short As[64][48];
  __shared__ unsigned short Bs[3][16][48];
  const int tid = threadIdx.x;
  const int rt = blockIdx.x / 19, jt = blockIdx.x % 19;
  const int R0 = rt * 64;
  const int j0 = jt * 16;
  const int w = tid >> 6, lane = tid & 63, q = lane >> 4, cl = lane & 15;
  const int srow = tid >> 2, sk = (tid & 3) * 8;
  const int bp = tid >> 6, bcol = (tid >> 2) & 15;

  f32x4 acc[3] = {{0,0,0,0},{0,0,0,0},{0,0,0,0}};
  for (int kt = 0; kt < 10; ++kt) {
    const int k0 = kt * 32;
    __syncthreads();
    *(uint4*)&As[srow][sk] = *(const uint4*)(hsb_bf_in + (size_t)(start + R0 + srow) * KP + k0 + sk);
    if (bp < 3) {
      uint4 wv = {0, 0, 0, 0};
      const int cg = j0 + bcol;
      if (cg < 300) wv = *(const uint4*)(WiouhT + (size_t)(bp * 300 + cg) * KP + k0 + sk);
      *(uint4*)&Bs[bp][bcol][sk] = wv;
    }
    __syncthreads();
    bf16x8 af = mk_frag(&As[16 * w + cl][4 * q], &As[16 * w + cl][16 + 4 * q]);
#pragma unroll
    for (int p = 0; p < 3; ++p) {
      bf16x8 bf = mk_frag(&Bs[p][cl][4 * q], &Bs[p][cl][16 + 4 * q]);
      acc[p] = __builtin_amdgcn_mfma_f32_16x16x32_bf16(af, bf, acc[p], 0, 0, 0);
    }
  }

  const int jj = j0 + cl;
  if (jj >= 300) return;
  float hsum = 0.f;
#pragma unroll
  for (int r = 0; r < 4; ++r) {
    const int rel = R0 + 16 * w + 4 * q + r;
    if (rel < M) {
      const int node = start + rel;
      float iv = acc[0][r] + xiou[(size_t)node * 900 + jj]       + b_iouh[jj];
      float ov = acc[1][r] + xiou[(size_t)node * 900 + 300 + jj] + b_iouh[300 + jj];
      float uv = acc[2][r] + xiou[(size_t)node * 900 + 600 + jj] + b_iouh[600 + jj];
      float cv = sigm(iv) * tanhf(uv) + fcb_in[(size_t)node * 300 + jj];
      float hv = sigm(ov) * tanhf(cv);
      c_cur[(size_t)rel * 300 + jj] = cv;
      h_bf[(size_t)rel * KP + jj] = f2bf(hv);
      hsum += hv;
    }
  }
  float tot = hsum + __shfl_xor(hsum, 16);
  if ((q & 1) == 0 && (R0 + 16 * w + (q >> 1) * 8) < M) {
    const int p = pstart + ((R0 + 16 * w) >> 3) + (q >> 1);
    hsb[(size_t)p * 300 + jj] = tot;
    hsb_bf_out[(size_t)p * KP + jj] = f2bf(tot);
  }
}

// ---------------- MFMA W_fh GEMM + fused f-gate + fc reduction ----------------
__global__ __launch_bounds__(256) void fcb_mfma(
    int M, int pstart,
    const unsigned short* __restrict__ h_bf, const unsigned short* __restrict__ WfhT,
    const float* __restrict__ c_cur, const float* __restrict__ b_fh,
    const float* __restrict__ fxo, float* __restrict__ fcb)
{
  __shared__ unsigned short As[64][48];
  __shared__ unsigned short Bs[16][48];
  const int tid = threadIdx.x;
  const int rt = blockIdx.x / 19, jt = blockIdx.x % 19;
  const int R0 = rt * 64;
  const int j0 = jt * 16;
  const int w = tid >> 6, lane = tid & 63, q = lane >> 4, cl = lane & 15;
  const int srow = tid >> 2, sk = (tid & 3) * 8;

  f32x4 acc = {0, 0, 0, 0};
  for (int kt = 0; kt < 10; ++kt) {
    const int k0 = kt * 32;
    __syncthreads();
    *(uint4*)&As[srow][sk] = *(const uint4*)(h_bf + (size_t)(R0 + srow) * KP + k0 + sk);
    if (tid < 64) {
      const int col = tid >> 2, ks = (tid & 3) * 8;
      uint4 wv = {0, 0, 0, 0};
      const int cg = j0 + col;
      if (cg < 300) wv = *(const uint4*)(WfhT + (size_t)cg * KP + k0 + ks);
      *(uint4*)&Bs[col][ks] = wv;
    }
    __syncthreads();
    bf16x8 af = mk_frag(&As[16 * w + cl][4 * q], &As[16 * w + cl][16 + 4 * q]);
    bf16x8 bf = mk_frag(&Bs[cl][4 * q], &Bs[cl][16 + 4 * q]);
    acc = __builtin_amdgcn_mfma_f32_16x16x32_bf16(af, bf, acc, 0, 0, 0);
  }

  const int jj = j0 + cl;
  if (jj >= 300) return;
  const int p = pstart + ((R0 + 16 * w) >> 3) + (q >> 1);
  float fc = 0.f;
#pragma unroll
  for (int r = 0; r < 4; ++r) {
    const int rel = R0 + 16 * w + 4 * q + r;
    if (rel < M) {
      const float add = b_fh[jj] + fxo[(size_t)p * 300 + jj];
      float f = sigm(acc[r] + add);
      fc += f * c_cur[(size_t)rel * 300 + jj];
    }
  }
  float tot = fc + __shfl_xor(fc, 16);
  if ((q & 1) == 0 && (R0 + 16 * w + (q >> 1) * 8) < M)
    fcb[(size_t)p * 300 + jj] = tot;
}

// ---------------- root: gates + W_lin head (1 block) ----------------
__global__ __launch_bounds__(1024) void root_kernel(
    const float* __restrict__ xiou,
    const float* __restrict__ W_iouh, const float* __restrict__ b_iouh,
    const float* __restrict__ hsb, const float* __restrict__ fcb,
    const float* __restrict__ W_lin, const float* __restrict__ b_lin,
    float* __restrict__ out)
{
  __shared__ float hs[300];
  __shared__ float siou[900];
  __shared__ float sc[300];
  const int tid = threadIdx.x;
  if (tid < 300) hs[tid] = hsb[tid];
  __syncthreads();
  if (tid < 900) {
    float acc = xiou[tid] + b_iouh[tid];
#pragma unroll 4
    for (int k = 0; k < 300; ++k) acc += hs[k] * W_iouh[(size_t)k * 900 + tid];
    siou[tid] = acc;
  }
  __syncthreads();
  if (tid < 300) {
    float cv = sigm(siou[tid]) * tanhf(siou[600 + tid]) + fcb[tid];
    float hv = sigm(siou[300 + tid]) * tanhf(cv);
    sc[tid] = cv;
    out[42 + tid] = hv;
  }
  __syncthreads();
  if (tid < 42) {
    float acc = b_lin[tid];
#pragma unroll 4
    for (int k = 0; k < 300; ++k) acc += sc[k] * W_lin[(size_t)k * 42 + tid];
    out[tid] = acc;
  }
}

extern "C" void kernel_launch(void* const* d_in, const int* in_sizes, int n_in,
                              void* d_out, int out_size, void* d_ws, size_t ws_size,
                              hipStream_t stream) {
  const int* tokens   = (const int*)d_in[0];
  const float* embed  = (const float*)d_in[3];
  const float* W_ioux = (const float*)d_in[4];
  const float* b_ioux = (const float*)d_in[5];
  const float* W_iouh = (const float*)d_in[6];
  const float* b_iouh = (const float*)d_in[7];
  const float* W_fx   = (const float*)d_in[8];
  const float* b_fx   = (const float*)d_in[9];
  const float* W_fh   = (const float*)d_in[10];
  const float* b_fh   = (const float*)d_in[11];
  const float* W_lin  = (const float*)d_in[12];
  const float* b_lin  = (const float*)d_in[13];
  float* out = (float*)d_out;

  float* ws    = (float*)d_ws;
  float* xiou  = ws;                                 // 585*900
  float* fxo   = xiou  + (size_t)NI * 900;           // 585*300
  float* hsb   = fxo   + (size_t)NI * 300;           // 585*300
  float* fcb   = hsb   + (size_t)NI * 300;           // 585*300
  float* c_cur = fcb   + (size_t)NI * 300;           // 4096*300
  unsigned short* Xb     = (unsigned short*)(c_cur + (size_t)4096 * 300);
  unsigned short* h_bf   = Xb     + (size_t)NN * KP;     // 4096*320
  unsigned short* WT     = h_bf   + (size_t)4096 * KP;   // 1200*320
  unsigned short* WfhT   = WT     + (size_t)1200 * KP;   // 300*320
  unsigned short* WiouhT = WfhT   + (size_t)300 * KP;    // 900*320
  unsigned short* hsb_bf = WiouhT + (size_t)900 * KP;    // 585*320

  // P: bf16 copies + pads
  prep_kernel<<<7374, 256, 0, stream>>>(tokens, embed, W_ioux, W_fx, W_fh, W_iouh,
      Xb, WT, WfhT, WiouhT, h_bf, hsb_bf);
  // K0: MFMA X-GEMM (internal xiou/fxo + leaf gates/c/h/hsb)
  fx_mfma<<<74 * 19, 256, 0, stream>>>(Xb, WT, b_ioux, b_fx, b_iouh,
      xiou, fxo, c_cur, h_bf, hsb, hsb_bf);
  // K1: fcb leaf (4096 children -> parents 73..584)
  fcb_mfma<<<64 * 19, 256, 0, stream>>>(4096, 73, h_bf, WfhT, c_cur, b_fh, fxo, fcb);
  // K2: ig 512 (nodes 73..584 -> parents 9..72)
  ig_mfma<<<8 * 19, 256, 0, stream>>>(512, 73, 9, hsb_bf, WiouhT, xiou, b_iouh, fcb,
      c_cur, h_bf, hsb, hsb_bf);
  // K3: fcb 512
  fcb_mfma<<<8 * 19, 256, 0, stream>>>(512, 9, h_bf, WfhT, c_cur, b_fh, fxo, fcb);
  // K4: ig 64 (nodes 9..72 -> parents 1..8)
  ig_mfma<<<19, 256, 0, stream>>>(64, 9, 1, hsb_bf, WiouhT, xiou, b_iouh, fcb,
      c_cur, h_bf, hsb, hsb_bf);
  // K5: fcb 64
  fcb_mfma<<<19, 256, 0, stream>>>(64, 1, h_bf, WfhT, c_cur, b_fh, fxo, fcb);
  // K6: ig 8 (nodes 1..8 -> root)
  ig_mfma<<<19, 256, 0, stream>>>(8, 1, 0, hsb_bf, WiouhT, xiou, b_iouh, fcb,
      c_cur, h_bf, hsb, hsb_bf);
  // K7: fcb 8 (root)
  fcb_mfma<<<19, 256, 0, stream>>>(8, 0, h_bf, WfhT, c_cur, b_fh, fxo, fcb);
  // K8: root
  root_kernel<<<1, 1024, 0, stream>>>(xiou, W_iouh, b_iouh, hsb, fcb, W_lin, b_lin, out);
}